// Round 2
// baseline (3385.405 us; speedup 1.0000x reference)
//
#include <hip/hip_runtime.h>
#include <hip/hip_bf16.h>
#include <cstdint>
#include <cstddef>

// Problem constants
constexpr int NB = 64;     // graphs (batch)
constexpr int NN = 1024;   // nodes per graph
constexpr int NE = 16384;  // edges per graph
constexpr int NH = 4;      // GAT heads
constexpr int HD = 32;     // GAT head dim
constexpr float C_BETA = 0.04879016417f;   // log(0.1/2 + 1)

// ---------------- degree / norm / CSR build ----------------

__global__ void init_deg_k(float* degw, float* degu, int* indeg) {
  int g = blockIdx.x * 256 + threadIdx.x;
  degw[g] = 1.0f;  // self loop weight 1
  degu[g] = 1.0f;
  indeg[g] = 0;
}

__global__ void accum_deg_k(const int* __restrict__ ei, const float* __restrict__ ew,
                            float* degw, float* degu, int* indeg) {
  int g = blockIdx.x * 256 + threadIdx.x;
  int b = g / NE, e = g % NE;
  int d = ei[(size_t)b * 2 * NE + NE + e];
  atomicAdd(&degw[b * NN + d], ew[(size_t)b * NE + e]);
  atomicAdd(&degu[b * NN + d], 1.0f);
  atomicAdd(&indeg[b * NN + d], 1);
}

__global__ void finish_dinv_k(float* degw, float* degu) {
  int g = blockIdx.x * 256 + threadIdx.x;
  degw[g] = rsqrtf(degw[g]);
  degu[g] = rsqrtf(degu[g]);
}

__global__ __launch_bounds__(1024) void scan_k(const int* __restrict__ indeg,
                                               int* rowptr, int* fill) {
  int b = blockIdx.x, t = threadIdx.x;
  __shared__ int sb[NN];
  int v = indeg[b * NN + t];
  sb[t] = v;
  __syncthreads();
  for (int off = 1; off < NN; off <<= 1) {
    int x = (t >= off) ? sb[t - off] : 0;
    __syncthreads();
    sb[t] += x;
    __syncthreads();
  }
  rowptr[b * (NN + 1) + t + 1] = sb[t];
  if (t == 0) rowptr[b * (NN + 1)] = 0;
  fill[b * NN + t] = 0;   // fill aliases indeg; safe: indeg consumed above
}

__global__ void scatter_k(const int* __restrict__ ei, int* fill,
                          const int* __restrict__ rowptr, int* eids) {
  int g = blockIdx.x * 256 + threadIdx.x;
  int b = g / NE, e = g % NE;
  int d = ei[(size_t)b * 2 * NE + NE + e];
  int pos = rowptr[b * (NN + 1) + d] + atomicAdd(&fill[b * NN + d], 1);
  eids[(size_t)b * NE + pos] = e;
}

__global__ void edge_norm_k(const int* __restrict__ ei, const float* __restrict__ ew,
                            const float* __restrict__ dw, const float* __restrict__ du,
                            float* wn, float* wun) {
  int g = blockIdx.x * 256 + threadIdx.x;
  int b = g / NE, e = g % NE;
  int s = ei[(size_t)b * 2 * NE + e];
  int d = ei[(size_t)b * 2 * NE + NE + e];
  wn[(size_t)b * NE + e]  = dw[b * NN + s] * ew[(size_t)b * NE + e] * dw[b * NN + d];
  wun[(size_t)b * NE + e] = du[b * NN + s] * du[b * NN + d];
}

// ---------------- fp32 tiled GEMM: C[M,N] = A[M,K] @ W[K,N] ----------------
// MODE 0: C = acc
// MODE 2: C = relu((1-beta)*Z + beta*acc)   (GCN2Conv epilogue; Z read at C coords)

template<int BM, int BN, int BK, int TM, int TN, int MODE>
__global__ void gemm_k(const float* __restrict__ A, const float* __restrict__ W,
                       const float* __restrict__ Z, float* __restrict__ C,
                       int M, int K, int N) {
  __shared__ float As[BK][BM + 1];
  __shared__ float Bs[BK][BN + 1];
  constexpr int TX = BN / TN;
  int tid = threadIdx.x;
  int tx = tid % TX;
  int ty = tid / TX;
  int bm = blockIdx.y * BM;
  int bn = blockIdx.x * BN;
  float acc[TM][TN] = {};
  for (int k0 = 0; k0 < K; k0 += BK) {
    for (int i = tid; i < BM * BK; i += 256) {
      int m = i / BK, k = i % BK;
      As[k][m] = (k0 + k < K) ? A[(size_t)(bm + m) * K + k0 + k] : 0.f;
    }
    for (int i = tid; i < BK * BN; i += 256) {
      int k = i / BN, n = i % BN;
      Bs[k][n] = (k0 + k < K) ? W[(size_t)(k0 + k) * N + bn + n] : 0.f;
    }
    __syncthreads();
#pragma unroll
    for (int k = 0; k < BK; ++k) {
      float ra[TM], rb[TN];
#pragma unroll
      for (int i = 0; i < TM; ++i) ra[i] = As[k][ty * TM + i];
#pragma unroll
      for (int j = 0; j < TN; ++j) rb[j] = Bs[k][tx * TN + j];
#pragma unroll
      for (int i = 0; i < TM; ++i)
#pragma unroll
        for (int j = 0; j < TN; ++j) acc[i][j] += ra[i] * rb[j];
    }
    __syncthreads();
  }
  for (int i = 0; i < TM; ++i)
    for (int j = 0; j < TN; ++j) {
      size_t idx = (size_t)(bm + ty * TM + i) * N + bn + tx * TN + j;
      if (MODE == 0) C[idx] = acc[i][j];
      else           C[idx] = fmaxf((1.f - C_BETA) * Z[idx] + C_BETA * acc[i][j], 0.f);
    }
}

// ---------------- graph propagation (dst-CSR gather) ----------------
// acc = dinv[i]^2 * in[i,c] + sum_e wn[e] * in[src[e],c]
// MODE 0: out = relu(acc + aux[c])            (aux = bias)
// MODE 1: out = 0.5*acc + 0.5*aux[node,c]     (aux = x0; GCN2Conv z)

template<int D, int MODE>
__global__ void prop_k(const float* __restrict__ in, float* __restrict__ out,
                       const int* __restrict__ ei, const float* __restrict__ wn,
                       const float* __restrict__ dinv, const int* __restrict__ rowptr,
                       const int* __restrict__ eids, const float* __restrict__ aux) {
  constexpr int NPB = 256 / D;
  int t = threadIdx.x;
  int c = t % D, lo = t / D;
  int node = blockIdx.x * NPB + lo;
  int b = node / NN, i = node % NN;
  const float* inb = in + (size_t)b * NN * D;
  float di = dinv[b * NN + i];
  float acc = di * di * inb[(size_t)i * D + c];
  int r0 = rowptr[b * (NN + 1) + i], r1 = rowptr[b * (NN + 1) + i + 1];
  const int* eb = eids + (size_t)b * NE;
  const float* wb = wn + (size_t)b * NE;
  const int* srcb = ei + (size_t)b * 2 * NE;
  for (int p = r0; p < r1; ++p) {
    int e = eb[p];
    acc += wb[e] * inb[(size_t)srcb[e] * D + c];
  }
  size_t oi = (size_t)node * D + c;
  if (MODE == 0) out[oi] = fmaxf(acc + aux[c], 0.f);
  else           out[oi] = 0.5f * acc + 0.5f * aux[oi];
}

// ---------------- GATv2 ----------------

__global__ void gat_logits_k(const float* __restrict__ xl, const float* __restrict__ xr,
                             const int* __restrict__ ei, const float* __restrict__ att,
                             float* __restrict__ lg, float* __restrict__ lgs) {
  int g = blockIdx.x * 256 + threadIdx.x;
  int h = g & 3;
  int r = g >> 2;
  int b = r / (NE + NN), e = r % (NE + NN);
  int s, d;
  if (e < NE) {
    s = ei[(size_t)b * 2 * NE + e];
    d = ei[(size_t)b * 2 * NE + NE + e];
  } else {
    s = d = e - NE;
  }
  const float* xs = xl + ((size_t)b * NN + s) * (NH * HD) + h * HD;
  const float* xd = xr + ((size_t)b * NN + d) * (NH * HD) + h * HD;
  const float* at = att + h * HD;
  float acc = 0.f;
#pragma unroll
  for (int cc = 0; cc < HD; ++cc) {
    float v = xs[cc] + xd[cc];
    v = v > 0.f ? v : 0.2f * v;
    acc += v * at[cc];
  }
  if (e < NE) lg[((size_t)b * NE + e) * NH + h] = acc;
  else        lgs[((size_t)b * NN + (e - NE)) * NH + h] = acc;
}

__global__ void gat_agg_k(const float* __restrict__ xl, const float* __restrict__ lg,
                          const float* __restrict__ lgs, const int* __restrict__ ei,
                          const int* __restrict__ rowptr, const int* __restrict__ eids,
                          const float* __restrict__ bg, float* __restrict__ out) {
  int b = blockIdx.x / NN, i = blockIdx.x % NN;
  int t = threadIdx.x;   // 128 = 4 heads * 32
  int h = t >> 5;
  int r0 = rowptr[b * (NN + 1) + i], r1 = rowptr[b * (NN + 1) + i + 1];
  const int* eb = eids + (size_t)b * NE;
  const int* srcb = ei + (size_t)b * 2 * NE;
  float ls = lgs[((size_t)b * NN + i) * NH + h];
  float m = ls;
  for (int p = r0; p < r1; ++p)
    m = fmaxf(m, lg[((size_t)b * NE + eb[p]) * NH + h]);
  float a = __expf(ls - m);
  float den = a;
  float acc = a * xl[((size_t)b * NN + i) * (NH * HD) + t];
  for (int p = r0; p < r1; ++p) {
    int e = eb[p];
    float av = __expf(lg[((size_t)b * NE + e) * NH + h] - m);
    den += av;
    acc += av * xl[((size_t)b * NN + srcb[e]) * (NH * HD) + t];
  }
  float o = acc / den + bg[t];
  out[((size_t)b * NN + i) * (NH * HD) + t] = fmaxf(o, 0.f);
}

// ---------------- pooled = column-sum(h7); out = pooled @ Wo + bo ----------------
// (diff-pool tail collapses: softmax over a size-1 axis gives sc == 1, and
//  softmax assignment rows sum to 1, so pooled = sum_i h7[i,:].)

__global__ void pool_out_k(const float* __restrict__ h7, const float* __restrict__ Wo,
                           const float* __restrict__ bo, float* __restrict__ out) {
  int b = blockIdx.x, t = threadIdx.x;  // 256 threads
  const float* hb = h7 + (size_t)b * NN * 256;
  float acc = 0.f;
  for (int i = 0; i < NN; ++i) acc += hb[(size_t)i * 256 + t];
  __shared__ float pooled[256];
  pooled[t] = acc;
  __syncthreads();
  if (t < 8) {
    float o = bo[t];
    for (int c = 0; c < 256; ++c) o += pooled[c] * Wo[c * 8 + t];
    out[b * 8 + t] = o;
  }
}

__global__ void zero_out_k(float* out, int n) {
  int g = blockIdx.x * 256 + threadIdx.x;
  if (g < n) out[g] = 0.f;
}

// ---------------- launch ----------------

extern "C" void kernel_launch(void* const* d_in, const int* in_sizes, int n_in,
                              void* d_out, int out_size, void* d_ws, size_t ws_size,
                              hipStream_t stream) {
  const float* x   = (const float*)d_in[0];
  const int*   ei  = (const int*)d_in[1];
  const float* ew  = (const float*)d_in[2];
  const float* W1  = (const float*)d_in[3];
  const float* b1  = (const float*)d_in[4];
  const float* W2  = (const float*)d_in[5];
  const float* b2  = (const float*)d_in[6];
  const float* W3  = (const float*)d_in[7];
  const float* b3  = (const float*)d_in[8];
  const float* W4  = (const float*)d_in[9];
  const float* b4  = (const float*)d_in[10];
  const float* Wl  = (const float*)d_in[11];
  const float* Wr  = (const float*)d_in[12];
  const float* att = (const float*)d_in[13];
  const float* bg  = (const float*)d_in[14];
  const float* Wg1 = (const float*)d_in[15];
  const float* Wm  = (const float*)d_in[16];
  const float* bm  = (const float*)d_in[17];
  const float* Wg2 = (const float*)d_in[18];
  // d_in[19..22] (Wp1,bp1,Wp2,bp2) cancel mathematically (see pool_out_k note)
  const float* Wo  = (const float*)d_in[23];
  const float* bo  = (const float*)d_in[24];
  float* out = (float*)d_out;

  const int M = NB * NN;

  // ---- workspace layout (exact): ~222 MB ----
  char* wp = (char*)d_ws;
  size_t used = 0;
  auto alloc = [&](size_t bytes) -> void* {
    void* p = (void*)wp;
    size_t a = (bytes + 255) & ~(size_t)255;
    wp += a; used += a;
    return p;
  };
  float* dinvw = (float*)alloc((size_t)NB * NN * 4);
  float* dinvu = (float*)alloc((size_t)NB * NN * 4);
  float* wn    = (float*)alloc((size_t)NB * NE * 4);
  float* wun   = (float*)alloc((size_t)NB * NE * 4);
  int*   indeg = (int*)alloc((size_t)NB * NN * 4);       // reused as fill
  int*   rowptr= (int*)alloc((size_t)NB * (NN + 1) * 4);
  int*   eids  = (int*)alloc((size_t)NB * NE * 4);
  float* lg    = (float*)alloc((size_t)NB * NE * NH * 4);
  float* lgs   = (float*)alloc((size_t)NB * NN * NH * 4);
  float* B1 = (float*)alloc((size_t)M * 256 * 4);  // h1
  float* B2 = (float*)alloc((size_t)M * 256 * 4);
  float* B3 = (float*)alloc((size_t)M * 256 * 4);
  float* B2a = B2, *B2b = B2 + (size_t)M * 128;
  float* B3a = B3, *B3b = B3 + (size_t)M * 128;

  if (used > ws_size) {  // defensive: clean fail instead of memory-fault abort
    zero_out_k<<<(out_size + 255) / 256, 256, 0, stream>>>(out, out_size);
    return;
  }

  // ---- CSR + norms ----
  init_deg_k<<<NB * NN / 256, 256, 0, stream>>>(dinvw, dinvu, indeg);
  accum_deg_k<<<NB * NE / 256, 256, 0, stream>>>(ei, ew, dinvw, dinvu, indeg);
  finish_dinv_k<<<NB * NN / 256, 256, 0, stream>>>(dinvw, dinvu);
  scan_k<<<NB, NN, 0, stream>>>(indeg, rowptr, indeg);
  scatter_k<<<NB * NE / 256, 256, 0, stream>>>(ei, indeg, rowptr, eids);
  edge_norm_k<<<NB * NE / 256, 256, 0, stream>>>(ei, ew, dinvw, dinvu, wn, wun);

  // ---- GCN stack ----
  gemm_k<64,64,16,4,4,0><<<dim3(4, M / 64), 256, 0, stream>>>(x, W1, nullptr, B2, M, 300, 256);
  prop_k<256,0><<<M, 256, 0, stream>>>(B2, B1, ei, wn, dinvw, rowptr, eids, b1);          // h1 = B1
  gemm_k<64,64,16,4,4,0><<<dim3(2, M / 64), 256, 0, stream>>>(B1, W2, nullptr, B2a, M, 256, 128);
  prop_k<128,0><<<M / 2, 256, 0, stream>>>(B2a, B3a, ei, wn, dinvw, rowptr, eids, b2);    // h2 = B3a
  gemm_k<64,64,16,4,4,0><<<dim3(1, M / 64), 256, 0, stream>>>(B3a, W3, nullptr, B2a, M, 128, 64);
  prop_k<64,0><<<M / 4, 256, 0, stream>>>(B2a, B3b, ei, wn, dinvw, rowptr, eids, b3);     // h3 = B3b
  gemm_k<64,32,16,4,2,0><<<dim3(1, M / 64), 256, 0, stream>>>(B3b, W4, nullptr, B2a, M, 64, 32);
  prop_k<32,0><<<M / 8, 256, 0, stream>>>(B2a, B2b, ei, wn, dinvw, rowptr, eids, b4);     // h4 = B2b

  // ---- GATv2 ----
  gemm_k<64,64,16,4,4,0><<<dim3(2, M / 64), 256, 0, stream>>>(B2b, Wl, nullptr, B3b, M, 32, 128);  // xl
  gemm_k<64,64,16,4,4,0><<<dim3(2, M / 64), 256, 0, stream>>>(B2b, Wr, nullptr, B2a, M, 32, 128);  // xr
  gat_logits_k<<<NB * (NE + NN) * NH / 256, 256, 0, stream>>>(B3b, B2a, ei, att, lg, lgs);
  gat_agg_k<<<NB * NN, 128, 0, stream>>>(B3b, lg, lgs, ei, rowptr, eids, bg, B2a);        // hg = B2a

  // ---- GCN2Conv #1 (x0 = h2 = B3a) ----
  prop_k<128,1><<<M / 2, 256, 0, stream>>>(B2a, B2b, ei, wn, dinvw, rowptr, eids, B3a);   // z1 = B2b
  gemm_k<64,64,16,4,4,2><<<dim3(2, M / 64), 256, 0, stream>>>(B2b, Wg1, B2b, B2a, M, 128, 128); // h5 = B2a

  // ---- GCNConv mid (unweighted norm) ----
  gemm_k<64,64,16,4,4,0><<<dim3(4, M / 64), 256, 0, stream>>>(B2a, Wm, nullptr, B3, M, 128, 256);
  prop_k<256,0><<<M, 256, 0, stream>>>(B3, B2, ei, wun, dinvu, rowptr, eids, bm);         // h6 = B2

  // ---- GCN2Conv #2 (x0 = h1 = B1) ----
  prop_k<256,1><<<M, 256, 0, stream>>>(B2, B3, ei, wn, dinvw, rowptr, eids, B1);          // z2 = B3
  gemm_k<64,64,16,4,4,2><<<dim3(4, M / 64), 256, 0, stream>>>(B3, Wg2, B3, B2, M, 256, 256); // h7 = B2

  // ---- collapsed diff-pool + output projection ----
  pool_out_k<<<NB, 256, 0, stream>>>(B2, Wo, bo, out);
}

// Round 3
// 862.087 us; speedup vs baseline: 3.9270x; 3.9270x over previous
//
#include <hip/hip_runtime.h>
#include <cstdint>
#include <cstddef>

constexpr int NB = 64;     // graphs
constexpr int NN = 1024;   // nodes/graph
constexpr int NE = 16384;  // edges/graph
constexpr int NH = 4;      // GAT heads
constexpr int HD = 32;     // GAT head dim
constexpr float C_BETA = 0.04879016417f;   // log(0.1/2 + 1)

typedef __attribute__((ext_vector_type(8))) short s8v;   // 8 bf16 (4 VGPRs)
typedef __attribute__((ext_vector_type(4))) float f4v;

__device__ inline float bf2f(ushort u){ union{uint u;float f;} v; v.u=((uint)u)<<16; return v.f; }
__device__ inline ushort f2bf(float f){ union{float f;uint u;} v; v.f=f; uint r=v.u+0x7fffu+((v.u>>16)&1u); return (ushort)(r>>16); }
__device__ inline void up8(uint4 x, float* o){
  o[0]=bf2f((ushort)x.x); o[1]=bf2f((ushort)(x.x>>16));
  o[2]=bf2f((ushort)x.y); o[3]=bf2f((ushort)(x.y>>16));
  o[4]=bf2f((ushort)x.z); o[5]=bf2f((ushort)(x.z>>16));
  o[6]=bf2f((ushort)x.w); o[7]=bf2f((ushort)(x.w>>16));
}
__device__ inline uint pk2(float a, float b){ return (uint)f2bf(a) | ((uint)f2bf(b)<<16); }
__device__ inline uint4 pk8(const float* f){
  uint4 v; v.x=pk2(f[0],f[1]); v.y=pk2(f[2],f[3]); v.z=pk2(f[4],f[5]); v.w=pk2(f[6],f[7]); return v;
}
// XCD-bijective swizzle: graph g -> XCD g/(NB/8); requires grid = NB*bpg
__device__ inline int swz8(int bid, int bpg){
  int xcd = bid & 7, j = bid >> 3;
  return (xcd * (NB/8) + j / bpg) * bpg + (j % bpg);
}

// ---------------- degree / CSR build (+ fused edge-norm packing) ----------------

__global__ void init_deg_k(float* degw, float* degu, int* indeg) {
  int g = blockIdx.x * 256 + threadIdx.x;
  degw[g] = 1.0f; degu[g] = 1.0f; indeg[g] = 0;
}

__global__ void accum_deg_k(const int* __restrict__ ei, const float* __restrict__ ew,
                            float* degw, float* degu, int* indeg) {
  int g = blockIdx.x * 256 + threadIdx.x;
  int b = g / NE, e = g % NE;
  int d = ei[(size_t)b * 2 * NE + NE + e];
  atomicAdd(&degw[b * NN + d], ew[(size_t)b * NE + e]);
  atomicAdd(&degu[b * NN + d], 1.0f);
  atomicAdd(&indeg[b * NN + d], 1);
}

__global__ void finish_dinv_k(float* degw, float* degu) {
  int g = blockIdx.x * 256 + threadIdx.x;
  degw[g] = rsqrtf(degw[g]);
  degu[g] = rsqrtf(degu[g]);
}

__global__ __launch_bounds__(1024) void scan_k(const int* __restrict__ indeg,
                                               int* rowptr, int* fill) {
  int b = blockIdx.x, t = threadIdx.x;
  __shared__ int sb[NN];
  sb[t] = indeg[b * NN + t];
  __syncthreads();
  for (int off = 1; off < NN; off <<= 1) {
    int x = (t >= off) ? sb[t - off] : 0;
    __syncthreads();
    sb[t] += x;
    __syncthreads();
  }
  rowptr[b * (NN + 1) + t + 1] = sb[t];
  if (t == 0) rowptr[b * (NN + 1)] = 0;
  fill[b * NN + t] = 0;
}

// scatter + edge-norm fused: packed per-dst arrays (src, w_norm, w_unnorm, orig edge id)
__global__ void scatter_k(const int* __restrict__ ei, const float* __restrict__ ew,
                          const float* __restrict__ dw, const float* __restrict__ du,
                          int* fill, const int* __restrict__ rowptr,
                          int* psrc, float* pwn, float* pwu, int* eids) {
  int g = blockIdx.x * 256 + threadIdx.x;
  int b = g / NE, e = g % NE;
  int s = ei[(size_t)b * 2 * NE + e];
  int d = ei[(size_t)b * 2 * NE + NE + e];
  int pos = rowptr[b * (NN + 1) + d] + atomicAdd(&fill[b * NN + d], 1);
  size_t o = (size_t)b * NE + pos;
  psrc[o] = s;
  pwn[o]  = dw[b * NN + s] * ew[(size_t)b * NE + e] * dw[b * NN + d];
  pwu[o]  = du[b * NN + s] * du[b * NN + d];
  eids[o] = e;
}

// ---------------- conversions ----------------

__global__ void xconv_k(const float* __restrict__ x, ushort* __restrict__ xbf) {
  int g = blockIdx.x * 256 + threadIdx.x;   // M*320
  int row = g / 320, c = g % 320;
  xbf[g] = (c < 300) ? f2bf(x[(size_t)row * 300 + c]) : (ushort)0;
}

__global__ void wconv_k(const float* __restrict__ W, ushort* __restrict__ Wt,
                        int K, int N, int Kp) {
  int g = blockIdx.x * 256 + threadIdx.x;
  if (g >= N * Kp) return;
  int n = g / Kp, k = g % Kp;
  Wt[g] = (k < K) ? f2bf(W[(size_t)k * N + n]) : (ushort)0;
}

// ---------------- MFMA bf16 GEMM: C[M,N] = A[M,K] @ W[K,N]  (Wt = W^T bf16) ----------------
// MODE 0: C = acc (bf16).  MODE 2: C = relu((1-beta)*Z + beta*acc) (GCN2 epilogue).

template<int NI, int MODE>
__global__ __launch_bounds__(256) void mgemm_k(const ushort* __restrict__ A,
    const ushort* __restrict__ Bt, const ushort* __restrict__ Z,
    ushort* __restrict__ C, int M, int K, int N) {
  constexpr int BN = NI * 32;
  __shared__ ushort As[128][40];   // pad to 80B rows: 2-way-free bank pattern
  __shared__ ushort Bs[BN][40];
  int tid = threadIdx.x;
  int wave = tid >> 6, lane = tid & 63;
  int bm = blockIdx.y * 128, bn = blockIdx.x * BN;
  int wm = (wave >> 1) * 64, wn = (wave & 1) * (NI * 16);
  f4v acc[4][NI];
#pragma unroll
  for (int a = 0; a < 4; ++a)
#pragma unroll
    for (int b = 0; b < NI; ++b)
#pragma unroll
      for (int q = 0; q < 4; ++q) acc[a][b][q] = 0.f;
  int r = lane & 15, kg = (lane >> 4) * 8;
  for (int k0 = 0; k0 < K; k0 += 32) {
#pragma unroll
    for (int c = tid; c < 512; c += 256) {
      int row = c >> 2, kc = (c & 3) * 8;
      *(uint4*)&As[row][kc] = *(const uint4*)&A[(size_t)(bm + row) * K + k0 + kc];
    }
#pragma unroll
    for (int c = tid; c < BN * 4; c += 256) {
      int col = c >> 2, kc = (c & 3) * 8;
      *(uint4*)&Bs[col][kc] = *(const uint4*)&Bt[(size_t)(bn + col) * K + k0 + kc];
    }
    __syncthreads();
    s8v af[4], bf[NI];
#pragma unroll
    for (int mi = 0; mi < 4; ++mi) af[mi] = *(const s8v*)&As[wm + mi * 16 + r][kg];
#pragma unroll
    for (int ni = 0; ni < NI; ++ni) bf[ni] = *(const s8v*)&Bs[wn + ni * 16 + r][kg];
#pragma unroll
    for (int mi = 0; mi < 4; ++mi)
#pragma unroll
      for (int ni = 0; ni < NI; ++ni)
        acc[mi][ni] = __builtin_amdgcn_mfma_f32_16x16x32_bf16(af[mi], bf[ni], acc[mi][ni], 0, 0, 0);
    __syncthreads();
  }
  int col = lane & 15, rowg = (lane >> 4) * 4;
#pragma unroll
  for (int mi = 0; mi < 4; ++mi)
#pragma unroll
    for (int ni = 0; ni < NI; ++ni)
#pragma unroll
      for (int q = 0; q < 4; ++q) {
        int row = bm + wm + mi * 16 + rowg + q;
        int cc = bn + wn + ni * 16 + col;
        size_t idx = (size_t)row * N + cc;
        float v = acc[mi][ni][q];
        if (MODE == 2) v = fmaxf((1.f - C_BETA) * bf2f(Z[idx]) + C_BETA * v, 0.f);
        C[idx] = f2bf(v);
      }
}

// ---------------- graph propagation (packed dst-CSR gather, bf16 I/O) ----------------
// acc = dinv[i]^2*in[i,:] + sum_p pw[p]*in[psrc[p],:]
// MODE 0: out = relu(acc + bias).  MODE 1: out = 0.5*acc + 0.5*x0.

template<int D, int MODE>
__global__ __launch_bounds__(256) void prop_k(const ushort* __restrict__ in,
    ushort* __restrict__ out, const int* __restrict__ psrc,
    const float* __restrict__ pw, const float* __restrict__ dinv,
    const int* __restrict__ rowptr, const float* __restrict__ bias,
    const ushort* __restrict__ x0) {
  constexpr int TPN = D / 8, NPB = 256 / TPN, BPG = NN / NPB;
  int t = threadIdx.x;
  int bid = swz8(blockIdx.x, BPG);
  int tn = t / TPN, cl = t % TPN;
  int node = bid * NPB + tn;
  int b = node >> 10, i = node & 1023;
  float di = dinv[node];
  float f[8], acc[8];
  uint4 ov = *(const uint4*)&in[(size_t)node * D + cl * 8];
  up8(ov, f);
  float w0 = di * di;
#pragma unroll
  for (int j = 0; j < 8; ++j) acc[j] = w0 * f[j];
  int r0 = rowptr[b * (NN + 1) + i], r1 = rowptr[b * (NN + 1) + i + 1];
  const int* ps = psrc + (size_t)b * NE;
  const float* pwb = pw + (size_t)b * NE;
  const ushort* inb = in + (size_t)b * NN * D;
  for (int p = r0; p < r1; ++p) {
    int s = ps[p]; float w = pwb[p];
    uint4 rv = *(const uint4*)&inb[(size_t)s * D + cl * 8];
    up8(rv, f);
#pragma unroll
    for (int j = 0; j < 8; ++j) acc[j] += w * f[j];
  }
  size_t ob = (size_t)node * D + cl * 8;
  if (MODE == 0) {
#pragma unroll
    for (int j = 0; j < 8; ++j) acc[j] = fmaxf(acc[j] + bias[cl * 8 + j], 0.f);
  } else {
    uint4 xv = *(const uint4*)&x0[ob];
    up8(xv, f);
#pragma unroll
    for (int j = 0; j < 8; ++j) acc[j] = 0.5f * acc[j] + 0.5f * f[j];
  }
  *(uint4*)&out[ob] = pk8(acc);
}

// ---------------- GATv2 ----------------

__global__ __launch_bounds__(256) void gat_logits_k(const ushort* __restrict__ xl,
    const ushort* __restrict__ xr, const int* __restrict__ ei,
    const float* __restrict__ att, float* __restrict__ lg, float* __restrict__ lgs) {
  constexpr int BPG = (NE + NN) * NH / 256;  // 272
  int bid = swz8(blockIdx.x, BPG);
  int b = bid / BPG, w = bid % BPG;
  int widx = w * 256 + threadIdx.x;
  int h = widx & 3, rr = widx >> 2;
  int s, d;
  if (rr < NE) { s = ei[(size_t)b * 2 * NE + rr]; d = ei[(size_t)b * 2 * NE + NE + rr]; }
  else s = d = rr - NE;
  const ushort* xs = xl + ((size_t)b * NN + s) * 128 + h * 32;
  const ushort* xd = xr + ((size_t)b * NN + d) * 128 + h * 32;
  const float* at = att + h * 32;
  float a = 0.f, f1[8], f2[8];
#pragma unroll
  for (int c4 = 0; c4 < 4; ++c4) {
    uint4 v1 = *(const uint4*)&xs[c4 * 8];
    uint4 v2 = *(const uint4*)&xd[c4 * 8];
    up8(v1, f1); up8(v2, f2);
#pragma unroll
    for (int j = 0; j < 8; ++j) {
      float v = f1[j] + f2[j];
      v = v > 0.f ? v : 0.2f * v;
      a += v * at[c4 * 8 + j];
    }
  }
  if (rr < NE) lg[((size_t)b * NE + rr) * NH + h] = a;
  else         lgs[((size_t)b * NN + (rr - NE)) * NH + h] = a;
}

__global__ __launch_bounds__(256) void gat_agg_k(const ushort* __restrict__ xl,
    const float* __restrict__ lg, const float* __restrict__ lgs,
    const int* __restrict__ psrc, const int* __restrict__ eids,
    const int* __restrict__ rowptr, const float* __restrict__ bg,
    ushort* __restrict__ out) {
  int bid = swz8(blockIdx.x, NN / 4);     // 4 nodes/block
  int t = threadIdx.x;
  int node = bid * 4 + (t >> 6);
  int lane = t & 63;
  int b = node >> 10, i = node & 1023;
  int h = lane >> 4;          // 2 channels/thread -> head = lane/16
  int ch = lane * 2;
  int r0 = rowptr[b * (NN + 1) + i], r1 = rowptr[b * (NN + 1) + i + 1];
  const int* eb = eids + (size_t)b * NE;
  const int* ps = psrc + (size_t)b * NE;
  float ls = lgs[((size_t)b * NN + i) * NH + h];
  float m = ls;
  for (int p = r0; p < r1; ++p)
    m = fmaxf(m, lg[((size_t)b * NE + eb[p]) * NH + h]);
  float a = __expf(ls - m);
  float den = a;
  uint ov = *(const uint*)&xl[((size_t)b * NN + i) * 128 + ch];
  float o0 = a * bf2f((ushort)ov), o1 = a * bf2f((ushort)(ov >> 16));
  for (int p = r0; p < r1; ++p) {
    int e = eb[p], s = ps[p];
    float av = __expf(lg[((size_t)b * NE + e) * NH + h] - m);
    den += av;
    uint v = *(const uint*)&xl[((size_t)b * NN + s) * 128 + ch];
    o0 += av * bf2f((ushort)v);
    o1 += av * bf2f((ushort)(v >> 16));
  }
  o0 = fmaxf(o0 / den + bg[ch], 0.f);
  o1 = fmaxf(o1 / den + bg[ch + 1], 0.f);
  *(uint*)&out[((size_t)b * NN + i) * 128 + ch] = pk2(o0, o1);
}

// ---------------- pooled = column-sum(h7); out = pooled @ Wo + bo ----------------
// (diff-pool tail collapses: softmax over size-1 axis == 1; assignment rows sum to 1.)

__global__ __launch_bounds__(256) void pool_out_k(const ushort* __restrict__ h7,
    const float* __restrict__ Wo, const float* __restrict__ bo, float* __restrict__ out) {
  int bgr = blockIdx.x, t = threadIdx.x;
  int rg = t >> 5, cl = t & 31;   // 8 row-groups x 32 chunk-lanes
  const ushort* hb = h7 + (size_t)bgr * NN * 256;
  float a[8] = {};
  float f[8];
  for (int r = rg; r < NN; r += 8) {
    uint4 v = *(const uint4*)&hb[(size_t)r * 256 + cl * 8];
    up8(v, f);
#pragma unroll
    for (int j = 0; j < 8; ++j) a[j] += f[j];
  }
  __shared__ float red[8][256];
#pragma unroll
  for (int j = 0; j < 8; ++j) red[rg][cl * 8 + j] = a[j];
  __syncthreads();
  float pooled = 0.f;
#pragma unroll
  for (int g = 0; g < 8; ++g) pooled += red[g][t];
  __shared__ float pv[256];
  pv[t] = pooled;
  __syncthreads();
  if (t < 8) {
    float o = bo[t];
    for (int c = 0; c < 256; ++c) o += pv[c] * Wo[c * 8 + t];
    out[bgr * 8 + t] = o;
  }
}

__global__ void zero_out_k(float* out, int n) {
  int g = blockIdx.x * 256 + threadIdx.x;
  if (g < n) out[g] = 0.f;
}

// ---------------- launch ----------------

extern "C" void kernel_launch(void* const* d_in, const int* in_sizes, int n_in,
                              void* d_out, int out_size, void* d_ws, size_t ws_size,
                              hipStream_t stream) {
  const float* x   = (const float*)d_in[0];
  const int*   ei  = (const int*)d_in[1];
  const float* ew  = (const float*)d_in[2];
  const float* W1  = (const float*)d_in[3];
  const float* b1  = (const float*)d_in[4];
  const float* W2  = (const float*)d_in[5];
  const float* b2  = (const float*)d_in[6];
  const float* W3  = (const float*)d_in[7];
  const float* b3  = (const float*)d_in[8];
  const float* W4  = (const float*)d_in[9];
  const float* b4  = (const float*)d_in[10];
  const float* Wl  = (const float*)d_in[11];
  const float* Wr  = (const float*)d_in[12];
  const float* att = (const float*)d_in[13];
  const float* bg  = (const float*)d_in[14];
  const float* Wg1 = (const float*)d_in[15];
  const float* Wm  = (const float*)d_in[16];
  const float* bm  = (const float*)d_in[17];
  const float* Wg2 = (const float*)d_in[18];
  const float* Wo  = (const float*)d_in[23];
  const float* bo  = (const float*)d_in[24];
  float* out = (float*)d_out;

  const int M = NB * NN;

  char* wp = (char*)d_ws;
  size_t used = 0;
  auto alloc = [&](size_t bytes) -> void* {
    void* p = (void*)wp;
    size_t a = (bytes + 255) & ~(size_t)255;
    wp += a; used += a;
    return p;
  };
  float* dinvw = (float*)alloc((size_t)NB * NN * 4);
  float* dinvu = (float*)alloc((size_t)NB * NN * 4);
  int*   indeg = (int*)alloc((size_t)NB * NN * 4);     // reused as fill
  int*   rowptr= (int*)alloc((size_t)NB * (NN + 1) * 4);
  int*   psrc  = (int*)alloc((size_t)NB * NE * 4);
  float* pwn   = (float*)alloc((size_t)NB * NE * 4);
  float* pwu   = (float*)alloc((size_t)NB * NE * 4);
  int*   eids  = (int*)alloc((size_t)NB * NE * 4);
  float* lg    = (float*)alloc((size_t)NB * NE * NH * 4);
  float* lgs   = (float*)alloc((size_t)NB * NN * NH * 4);
  ushort* xbf  = (ushort*)alloc((size_t)M * 320 * 2);
  ushort* Wt1  = (ushort*)alloc((size_t)256 * 320 * 2);
  ushort* Wt2  = (ushort*)alloc((size_t)128 * 256 * 2);
  ushort* Wt3  = (ushort*)alloc((size_t)64 * 128 * 2);
  ushort* Wt4  = (ushort*)alloc((size_t)32 * 64 * 2);
  ushort* Wtl  = (ushort*)alloc((size_t)128 * 32 * 2);
  ushort* Wtr  = (ushort*)alloc((size_t)128 * 32 * 2);
  ushort* Wtg1 = (ushort*)alloc((size_t)128 * 128 * 2);
  ushort* Wtm  = (ushort*)alloc((size_t)256 * 128 * 2);
  ushort* Wtg2 = (ushort*)alloc((size_t)256 * 256 * 2);
  ushort* B1 = (ushort*)alloc((size_t)M * 256 * 2);   // h1
  ushort* B2 = (ushort*)alloc((size_t)M * 256 * 2);
  ushort* B3 = (ushort*)alloc((size_t)M * 256 * 2);
  ushort* B2a = B2, *B2b = B2 + (size_t)M * 128;
  ushort* B3a = B3, *B3b = B3 + (size_t)M * 128;

  if (used > ws_size) {
    zero_out_k<<<(out_size + 255) / 256, 256, 0, stream>>>(out, out_size);
    return;
  }

  // ---- CSR + norms (packed) ----
  init_deg_k<<<NB * NN / 256, 256, 0, stream>>>(dinvw, dinvu, indeg);
  accum_deg_k<<<NB * NE / 256, 256, 0, stream>>>(ei, ew, dinvw, dinvu, indeg);
  finish_dinv_k<<<NB * NN / 256, 256, 0, stream>>>(dinvw, dinvu);
  scan_k<<<NB, NN, 0, stream>>>(indeg, rowptr, indeg);
  scatter_k<<<NB * NE / 256, 256, 0, stream>>>(ei, ew, dinvw, dinvu, indeg, rowptr,
                                               psrc, pwn, pwu, eids);

  // ---- conversions ----
  xconv_k<<<(int)((size_t)M * 320 / 256), 256, 0, stream>>>(x, xbf);
  wconv_k<<<(256 * 320 + 255) / 256, 256, 0, stream>>>(W1, Wt1, 300, 256, 320);
  wconv_k<<<(128 * 256 + 255) / 256, 256, 0, stream>>>(W2, Wt2, 256, 128, 256);
  wconv_k<<<(64 * 128 + 255) / 256, 256, 0, stream>>>(W3, Wt3, 128, 64, 128);
  wconv_k<<<(32 * 64 + 255) / 256, 256, 0, stream>>>(W4, Wt4, 64, 32, 64);
  wconv_k<<<(128 * 32 + 255) / 256, 256, 0, stream>>>(Wl, Wtl, 32, 128, 32);
  wconv_k<<<(128 * 32 + 255) / 256, 256, 0, stream>>>(Wr, Wtr, 32, 128, 32);
  wconv_k<<<(128 * 128 + 255) / 256, 256, 0, stream>>>(Wg1, Wtg1, 128, 128, 128);
  wconv_k<<<(256 * 128 + 255) / 256, 256, 0, stream>>>(Wm, Wtm, 128, 256, 128);
  wconv_k<<<(256 * 256 + 255) / 256, 256, 0, stream>>>(Wg2, Wtg2, 256, 256, 256);

  // ---- GCN stack ----
  mgemm_k<4,0><<<dim3(2, M / 128), 256, 0, stream>>>(xbf, Wt1, nullptr, B2, M, 320, 256);
  prop_k<256,0><<<M / 8, 256, 0, stream>>>(B2, B1, psrc, pwn, dinvw, rowptr, b1, nullptr);   // h1
  mgemm_k<4,0><<<dim3(1, M / 128), 256, 0, stream>>>(B1, Wt2, nullptr, B2a, M, 256, 128);
  prop_k<128,0><<<M / 16, 256, 0, stream>>>(B2a, B3a, psrc, pwn, dinvw, rowptr, b2, nullptr); // h2
  mgemm_k<2,0><<<dim3(1, M / 128), 256, 0, stream>>>(B3a, Wt3, nullptr, B2a, M, 128, 64);
  prop_k<64,0><<<M / 32, 256, 0, stream>>>(B2a, B3b, psrc, pwn, dinvw, rowptr, b3, nullptr);  // h3
  mgemm_k<1,0><<<dim3(1, M / 128), 256, 0, stream>>>(B3b, Wt4, nullptr, B2a, M, 64, 32);
  prop_k<32,0><<<M / 64, 256, 0, stream>>>(B2a, B2b, psrc, pwn, dinvw, rowptr, b4, nullptr);  // h4

  // ---- GATv2 ----
  mgemm_k<4,0><<<dim3(1, M / 128), 256, 0, stream>>>(B2b, Wtl, nullptr, B3b, M, 32, 128);   // xl
  mgemm_k<4,0><<<dim3(1, M / 128), 256, 0, stream>>>(B2b, Wtr, nullptr, B2a, M, 32, 128);   // xr
  gat_logits_k<<<NB * ((NE + NN) * NH / 256), 256, 0, stream>>>(B3b, B2a, ei, att, lg, lgs);
  gat_agg_k<<<M / 4, 256, 0, stream>>>(B3b, lg, lgs, psrc, eids, rowptr, bg, B2a);          // hg

  // ---- GCN2Conv #1 (x0 = h2 = B3a) ----
  prop_k<128,1><<<M / 16, 256, 0, stream>>>(B2a, B2b, psrc, pwn, dinvw, rowptr, nullptr, B3a); // z1
  mgemm_k<4,2><<<dim3(1, M / 128), 256, 0, stream>>>(B2b, Wtg1, B2b, B2a, M, 128, 128);     // h5

  // ---- GCNConv mid (unweighted norm) ----
  mgemm_k<4,0><<<dim3(2, M / 128), 256, 0, stream>>>(B2a, Wtm, nullptr, B3, M, 128, 256);
  prop_k<256,0><<<M / 8, 256, 0, stream>>>(B3, B2, psrc, pwu, dinvu, rowptr, bm, nullptr);  // h6

  // ---- GCN2Conv #2 (x0 = h1 = B1) ----
  prop_k<256,1><<<M / 8, 256, 0, stream>>>(B2, B3, psrc, pwn, dinvw, rowptr, nullptr, B1);  // z2
  mgemm_k<4,2><<<dim3(2, M / 128), 256, 0, stream>>>(B3, Wtg2, B3, B2, M, 256, 256);        // h7

  // ---- collapsed diff-pool + output projection ----
  pool_out_k<<<NB, 256, 0, stream>>>(B2, Wo, bo, out);
}

// Round 4
// 758.824 us; speedup vs baseline: 4.4614x; 1.1361x over previous
//
#include <hip/hip_runtime.h>
#include <cstdint>
#include <cstddef>

constexpr int NB = 64;     // graphs
constexpr int NN = 1024;   // nodes/graph
constexpr int NE = 16384;  // edges/graph
constexpr int NH = 4;      // GAT heads
constexpr float C_BETA = 0.04879016417f;   // log(0.1/2 + 1)

typedef __attribute__((ext_vector_type(8))) short s8v;   // 8 bf16 (4 VGPRs)
typedef __attribute__((ext_vector_type(4))) float f4v;

__device__ inline float bf2f(ushort u){ union{uint u;float f;} v; v.u=((uint)u)<<16; return v.f; }
__device__ inline ushort f2bf(float f){ union{float f;uint u;} v; v.f=f; uint r=v.u+0x7fffu+((v.u>>16)&1u); return (ushort)(r>>16); }
__device__ inline void up8(uint4 x, float* o){
  o[0]=bf2f((ushort)x.x); o[1]=bf2f((ushort)(x.x>>16));
  o[2]=bf2f((ushort)x.y); o[3]=bf2f((ushort)(x.y>>16));
  o[4]=bf2f((ushort)x.z); o[5]=bf2f((ushort)(x.z>>16));
  o[6]=bf2f((ushort)x.w); o[7]=bf2f((ushort)(x.w>>16));
}
__device__ inline uint pk2(float a, float b){ return (uint)f2bf(a) | ((uint)f2bf(b)<<16); }
__device__ inline uint4 pk8(const float* f){
  uint4 v; v.x=pk2(f[0],f[1]); v.y=pk2(f[2],f[3]); v.z=pk2(f[4],f[5]); v.w=pk2(f[6],f[7]); return v;
}
// XCD-bijective swizzle: graph g -> XCD g/(NB/8); requires grid = NB*bpg
__device__ inline int swz8(int bid, int bpg){
  int xcd = bid & 7, j = bid >> 3;
  return (xcd * (NB/8) + j / bpg) * bpg + (j % bpg);
}

// ---------------- degree / CSR build (+ fused edge-norm packing) ----------------

__global__ void init_deg_k(float* degw, int* indeg) {
  int g = blockIdx.x * 256 + threadIdx.x;
  degw[g] = 1.0f; indeg[g] = 0;
}

__global__ void accum_deg_k(const int* __restrict__ ei, const float* __restrict__ ew,
                            float* degw, int* indeg) {
  int g = blockIdx.x * 256 + threadIdx.x;
  int b = g / NE, e = g % NE;
  int d = ei[(size_t)b * 2 * NE + NE + e];
  atomicAdd(&degw[b * NN + d], ew[(size_t)b * NE + e]);
  atomicAdd(&indeg[b * NN + d], 1);
}

__global__ void finish_dinv_k(float* degw, const int* __restrict__ indeg, float* dinvu) {
  int g = blockIdx.x * 256 + threadIdx.x;
  degw[g] = rsqrtf(degw[g]);
  dinvu[g] = rsqrtf(1.0f + (float)indeg[g]);   // unweighted deg = count + self
}

__global__ __launch_bounds__(1024) void scan_k(const int* __restrict__ indeg,
                                               int* rowptr, int* fill) {
  int b = blockIdx.x, t = threadIdx.x;
  __shared__ int sb[NN];
  sb[t] = indeg[b * NN + t];
  __syncthreads();
  for (int off = 1; off < NN; off <<= 1) {
    int x = (t >= off) ? sb[t - off] : 0;
    __syncthreads();
    sb[t] += x;
    __syncthreads();
  }
  rowptr[b * (NN + 1) + t + 1] = sb[t];
  if (t == 0) rowptr[b * (NN + 1)] = 0;
  fill[b * NN + t] = 0;
}

// scatter + edge-norm fused: packed per-dst arrays (src, dst, w_norm, w_unnorm)
__global__ void scatter_k(const int* __restrict__ ei, const float* __restrict__ ew,
                          const float* __restrict__ dw, const float* __restrict__ du,
                          int* fill, const int* __restrict__ rowptr,
                          int* psrc, int* pdst, float* pwn, float* pwu) {
  int g = blockIdx.x * 256 + threadIdx.x;
  int b = g / NE, e = g % NE;
  int s = ei[(size_t)b * 2 * NE + e];
  int d = ei[(size_t)b * 2 * NE + NE + e];
  int pos = rowptr[b * (NN + 1) + d] + atomicAdd(&fill[b * NN + d], 1);
  size_t o = (size_t)b * NE + pos;
  psrc[o] = s;
  pdst[o] = d;
  pwn[o]  = dw[b * NN + s] * ew[(size_t)b * NE + e] * dw[b * NN + d];
  pwu[o]  = du[b * NN + s] * du[b * NN + d];
}

// ---------------- conversions ----------------

__global__ void xconv_k(const float* __restrict__ x, ushort* __restrict__ xbf) {
  int g = blockIdx.x * 256 + threadIdx.x;   // M*320
  int row = g / 320, c = g % 320;
  xbf[g] = (c < 300) ? f2bf(x[(size_t)row * 300 + c]) : (ushort)0;
}

__global__ void wconv_k(const float* __restrict__ W, ushort* __restrict__ Wt,
                        int K, int N, int Kp) {
  int g = blockIdx.x * 256 + threadIdx.x;
  if (g >= N * Kp) return;
  int n = g / Kp, k = g % Kp;
  Wt[g] = (k < K) ? f2bf(W[(size_t)k * N + n]) : (ushort)0;
}

// ---------------- MFMA bf16 GEMM: C[M,N] = A[M,K] @ W[K,N]  (Wt = W^T bf16) ----------------
// MODE 0: C = acc (bf16).  MODE 2: C = relu((1-beta)*Z + beta*acc) (GCN2 epilogue).

template<int NI, int MODE>
__global__ __launch_bounds__(256) void mgemm_k(const ushort* __restrict__ A,
    const ushort* __restrict__ Bt, const ushort* __restrict__ Z,
    ushort* __restrict__ C, int M, int K, int N) {
  constexpr int BN = NI * 32;
  __shared__ ushort As[128][40];   // pad to 80B rows: 2-way-free bank pattern
  __shared__ ushort Bs[BN][40];
  int tid = threadIdx.x;
  int wave = tid >> 6, lane = tid & 63;
  int bm = blockIdx.y * 128, bn = blockIdx.x * BN;
  int wm = (wave >> 1) * 64, wn = (wave & 1) * (NI * 16);
  f4v acc[4][NI];
#pragma unroll
  for (int a = 0; a < 4; ++a)
#pragma unroll
    for (int b = 0; b < NI; ++b)
#pragma unroll
      for (int q = 0; q < 4; ++q) acc[a][b][q] = 0.f;
  int r = lane & 15, kg = (lane >> 4) * 8;
  for (int k0 = 0; k0 < K; k0 += 32) {
#pragma unroll
    for (int c = tid; c < 512; c += 256) {
      int row = c >> 2, kc = (c & 3) * 8;
      *(uint4*)&As[row][kc] = *(const uint4*)&A[(size_t)(bm + row) * K + k0 + kc];
    }
#pragma unroll
    for (int c = tid; c < BN * 4; c += 256) {
      int col = c >> 2, kc = (c & 3) * 8;
      *(uint4*)&Bs[col][kc] = *(const uint4*)&Bt[(size_t)(bn + col) * K + k0 + kc];
    }
    __syncthreads();
    s8v af[4], bf[NI];
#pragma unroll
    for (int mi = 0; mi < 4; ++mi) af[mi] = *(const s8v*)&As[wm + mi * 16 + r][kg];
#pragma unroll
    for (int ni = 0; ni < NI; ++ni) bf[ni] = *(const s8v*)&Bs[wn + ni * 16 + r][kg];
#pragma unroll
    for (int mi = 0; mi < 4; ++mi)
#pragma unroll
      for (int ni = 0; ni < NI; ++ni)
        acc[mi][ni] = __builtin_amdgcn_mfma_f32_16x16x32_bf16(af[mi], bf[ni], acc[mi][ni], 0, 0, 0);
    __syncthreads();
  }
  int col = lane & 15, rowg = (lane >> 4) * 4;
#pragma unroll
  for (int mi = 0; mi < 4; ++mi)
#pragma unroll
    for (int ni = 0; ni < NI; ++ni)
#pragma unroll
      for (int q = 0; q < 4; ++q) {
        int row = bm + wm + mi * 16 + rowg + q;
        int cc = bn + wn + ni * 16 + col;
        size_t idx = (size_t)row * N + cc;
        float v = acc[mi][ni][q];
        if (MODE == 2) v = fmaxf((1.f - C_BETA) * bf2f(Z[idx]) + C_BETA * v, 0.f);
        C[idx] = f2bf(v);
      }
}

// ---------------- graph propagation (packed dst-CSR gather, bf16 I/O) ----------------
// acc = dinv[i]^2*in[i,:] + sum_p pw[p]*in[psrc[p],:]
// MODE 0: out = relu(acc + bias).  MODE 1: out = 0.5*acc + 0.5*x0.

template<int D, int MODE>
__global__ __launch_bounds__(256) void prop_k(const ushort* __restrict__ in,
    ushort* __restrict__ out, const int* __restrict__ psrc,
    const float* __restrict__ pw, const float* __restrict__ dinv,
    const int* __restrict__ rowptr, const float* __restrict__ bias,
    const ushort* __restrict__ x0) {
  constexpr int TPN = D / 8, NPB = 256 / TPN, BPG = NN / NPB;
  int t = threadIdx.x;
  int bid = swz8(blockIdx.x, BPG);
  int tn = t / TPN, cl = t % TPN;
  int node = bid * NPB + tn;
  int b = node >> 10, i = node & 1023;
  float di = dinv[node];
  float f[8], acc[8];
  uint4 ov = *(const uint4*)&in[(size_t)node * D + cl * 8];
  up8(ov, f);
  float w0 = di * di;
#pragma unroll
  for (int j = 0; j < 8; ++j) acc[j] = w0 * f[j];
  int r0 = rowptr[b * (NN + 1) + i], r1 = rowptr[b * (NN + 1) + i + 1];
  const int* ps = psrc + (size_t)b * NE;
  const float* pwb = pw + (size_t)b * NE;
  const ushort* inb = in + (size_t)b * NN * D;
  int p = r0;
  for (; p + 2 <= r1; p += 2) {      // 2-way unroll: independent load pairs
    int s0 = ps[p], s1 = ps[p + 1];
    float wa = pwb[p], wb2 = pwb[p + 1];
    uint4 rv0 = *(const uint4*)&inb[(size_t)s0 * D + cl * 8];
    uint4 rv1 = *(const uint4*)&inb[(size_t)s1 * D + cl * 8];
    up8(rv0, f);
#pragma unroll
    for (int j = 0; j < 8; ++j) acc[j] += wa * f[j];
    up8(rv1, f);
#pragma unroll
    for (int j = 0; j < 8; ++j) acc[j] += wb2 * f[j];
  }
  if (p < r1) {
    int s = ps[p]; float w = pwb[p];
    uint4 rv = *(const uint4*)&inb[(size_t)s * D + cl * 8];
    up8(rv, f);
#pragma unroll
    for (int j = 0; j < 8; ++j) acc[j] += w * f[j];
  }
  size_t ob = (size_t)node * D + cl * 8;
  if (MODE == 0) {
#pragma unroll
    for (int j = 0; j < 8; ++j) acc[j] = fmaxf(acc[j] + bias[cl * 8 + j], 0.f);
  } else {
    uint4 xv = *(const uint4*)&x0[ob];
    up8(xv, f);
#pragma unroll
    for (int j = 0; j < 8; ++j) acc[j] = 0.5f * acc[j] + 0.5f * f[j];
  }
  *(uint4*)&out[ob] = pk8(acc);
}

// ---------------- GATv2 (3-stage: packed logits -> alpha -> gather) ----------------
// xlr layout: [node][256]: ch 0-127 = xl, 128-255 = xr

__global__ __launch_bounds__(256) void gat_logits_k(const ushort* __restrict__ xlr,
    const int* __restrict__ psrc, const int* __restrict__ pdst,
    const float* __restrict__ att, float* __restrict__ lg, float* __restrict__ lgs) {
  constexpr int BPG = (NE + NN) * NH / 256;  // 272
  int bid = swz8(blockIdx.x, BPG);
  int b = bid / BPG, w = bid % BPG;
  int widx = w * 256 + threadIdx.x;
  int h = widx & 3, rr = widx >> 2;
  int s, d;
  if (rr < NE) { s = psrc[(size_t)b * NE + rr]; d = pdst[(size_t)b * NE + rr]; }
  else s = d = rr - NE;
  const ushort* xs = xlr + ((size_t)b * NN + s) * 256 + h * 32;
  const ushort* xd = xlr + ((size_t)b * NN + d) * 256 + 128 + h * 32;
  const float* at = att + h * 32;
  float a = 0.f, f1[8], f2[8];
#pragma unroll
  for (int c4 = 0; c4 < 4; ++c4) {
    uint4 v1 = *(const uint4*)&xs[c4 * 8];
    uint4 v2 = *(const uint4*)&xd[c4 * 8];
    up8(v1, f1); up8(v2, f2);
#pragma unroll
    for (int j = 0; j < 8; ++j) {
      float v = f1[j] + f2[j];
      v = v > 0.f ? v : 0.2f * v;
      a += v * at[c4 * 8 + j];
    }
  }
  if (rr < NE) lg[((size_t)b * NE + rr) * NH + h] = a;
  else         lgs[((size_t)b * NN + (rr - NE)) * NH + h] = a;
}

// per node: max + exp + den; rewrites lg/lgs in place with UNNORMALIZED exp; writes den
__global__ __launch_bounds__(256) void gat_alpha_k(float* __restrict__ lg,
    float* __restrict__ lgs, const int* __restrict__ rowptr, float* __restrict__ dden) {
  int bid = swz8(blockIdx.x, NN / 256);   // 4 blocks/graph
  int node = bid * 256 + threadIdx.x;
  int b = node >> 10, i = node & 1023;
  int r0 = rowptr[b * (NN + 1) + i], r1 = rowptr[b * (NN + 1) + i + 1];
  float* lgb = lg + (size_t)b * NE * NH;
  float4 m = *(float4*)&lgs[(size_t)node * NH];
  for (int p = r0; p < r1; ++p) {
    float4 v = *(float4*)&lgb[(size_t)p * NH];
    m.x = fmaxf(m.x, v.x); m.y = fmaxf(m.y, v.y);
    m.z = fmaxf(m.z, v.z); m.w = fmaxf(m.w, v.w);
  }
  float4 es = *(float4*)&lgs[(size_t)node * NH];
  es.x = __expf(es.x - m.x); es.y = __expf(es.y - m.y);
  es.z = __expf(es.z - m.z); es.w = __expf(es.w - m.w);
  *(float4*)&lgs[(size_t)node * NH] = es;
  float4 den = es;
  for (int p = r0; p < r1; ++p) {
    float4 v = *(float4*)&lgb[(size_t)p * NH];
    v.x = __expf(v.x - m.x); v.y = __expf(v.y - m.y);
    v.z = __expf(v.z - m.z); v.w = __expf(v.w - m.w);
    den.x += v.x; den.y += v.y; den.z += v.z; den.w += v.w;
    *(float4*)&lgb[(size_t)p * NH] = v;
  }
  *(float4*)&dden[(size_t)node * NH] = den;
}

// weighted gather: out = relu((e_self*xl[i] + sum e_p*xl[src]) / den + bg)
__global__ __launch_bounds__(256) void gat_gather_k(const ushort* __restrict__ xlr,
    const float* __restrict__ lg, const float* __restrict__ lgs,
    const float* __restrict__ dden, const int* __restrict__ psrc,
    const int* __restrict__ rowptr, const float* __restrict__ bg,
    ushort* __restrict__ out) {
  int bid = swz8(blockIdx.x, NN / 16);   // 16 nodes/block, 16 thr/node x 8ch
  int t = threadIdx.x;
  int tn = t >> 4, cl = t & 15;
  int node = bid * 16 + tn;
  int b = node >> 10, i = node & 1023;
  int h = cl >> 2, ch = cl * 8;
  int r0 = rowptr[b * (NN + 1) + i], r1 = rowptr[b * (NN + 1) + i + 1];
  const ushort* xb = xlr + (size_t)b * NN * 256;
  const int* ps = psrc + (size_t)b * NE;
  const float* lgb = lg + (size_t)b * NE * NH;
  float f[8], acc[8];
  float es = lgs[(size_t)node * NH + h];
  uint4 sv = *(const uint4*)&xb[(size_t)i * 256 + ch];
  up8(sv, f);
#pragma unroll
  for (int j = 0; j < 8; ++j) acc[j] = es * f[j];
  int p = r0;
  for (; p + 2 <= r1; p += 2) {
    int s0 = ps[p], s1 = ps[p + 1];
    float e0 = lgb[(size_t)p * NH + h], e1 = lgb[(size_t)(p + 1) * NH + h];
    uint4 v0 = *(const uint4*)&xb[(size_t)s0 * 256 + ch];
    uint4 v1 = *(const uint4*)&xb[(size_t)s1 * 256 + ch];
    up8(v0, f);
#pragma unroll
    for (int j = 0; j < 8; ++j) acc[j] += e0 * f[j];
    up8(v1, f);
#pragma unroll
    for (int j = 0; j < 8; ++j) acc[j] += e1 * f[j];
  }
  if (p < r1) {
    int s = ps[p];
    float e = lgb[(size_t)p * NH + h];
    uint4 v = *(const uint4*)&xb[(size_t)s * 256 + ch];
    up8(v, f);
#pragma unroll
    for (int j = 0; j < 8; ++j) acc[j] += e * f[j];
  }
  float inv = 1.f / dden[(size_t)node * NH + h];
#pragma unroll
  for (int j = 0; j < 8; ++j) acc[j] = fmaxf(acc[j] * inv + bg[ch + j], 0.f);
  *(uint4*)&out[(size_t)node * 128 + ch] = pk8(acc);
}

// ---------------- pooled = column-sum(h7); out = pooled @ Wo + bo ----------------
// (diff-pool tail collapses: softmax over size-1 axis == 1; assignment rows sum to 1.)

__global__ __launch_bounds__(256) void pool_out_k(const ushort* __restrict__ h7,
    const float* __restrict__ Wo, const float* __restrict__ bo, float* __restrict__ out) {
  int bgr = blockIdx.x, t = threadIdx.x;
  int rg = t >> 5, cl = t & 31;   // 8 row-groups x 32 chunk-lanes
  const ushort* hb = h7 + (size_t)bgr * NN * 256;
  float a[8] = {};
  float f[8];
  for (int r = rg; r < NN; r += 8) {
    uint4 v = *(const uint4*)&hb[(size_t)r * 256 + cl * 8];
    up8(v, f);
#pragma unroll
    for (int j = 0; j < 8; ++j) a[j] += f[j];
  }
  __shared__ float red[8][256];
#pragma unroll
  for (int j = 0; j < 8; ++j) red[rg][cl * 8 + j] = a[j];
  __syncthreads();
  float pooled = 0.f;
#pragma unroll
  for (int g = 0; g < 8; ++g) pooled += red[g][t];
  __shared__ float pv[256];
  pv[t] = pooled;
  __syncthreads();
  if (t < 8) {
    float o = bo[t];
    for (int c = 0; c < 256; ++c) o += pv[c] * Wo[c * 8 + t];
    out[bgr * 8 + t] = o;
  }
}

__global__ void zero_out_k(float* out, int n) {
  int g = blockIdx.x * 256 + threadIdx.x;
  if (g < n) out[g] = 0.f;
}

// ---------------- launch ----------------

extern "C" void kernel_launch(void* const* d_in, const int* in_sizes, int n_in,
                              void* d_out, int out_size, void* d_ws, size_t ws_size,
                              hipStream_t stream) {
  const float* x   = (const float*)d_in[0];
  const int*   ei  = (const int*)d_in[1];
  const float* ew  = (const float*)d_in[2];
  const float* W1  = (const float*)d_in[3];
  const float* b1  = (const float*)d_in[4];
  const float* W2  = (const float*)d_in[5];
  const float* b2  = (const float*)d_in[6];
  const float* W3  = (const float*)d_in[7];
  const float* b3  = (const float*)d_in[8];
  const float* W4  = (const float*)d_in[9];
  const float* b4  = (const float*)d_in[10];
  const float* Wl  = (const float*)d_in[11];
  const float* Wr  = (const float*)d_in[12];
  const float* att = (const float*)d_in[13];
  const float* bg  = (const float*)d_in[14];
  const float* Wg1 = (const float*)d_in[15];
  const float* Wm  = (const float*)d_in[16];
  const float* bm  = (const float*)d_in[17];
  const float* Wg2 = (const float*)d_in[18];
  const float* Wo  = (const float*)d_in[23];
  const float* bo  = (const float*)d_in[24];
  float* out = (float*)d_out;

  const int M = NB * NN;

  char* wp = (char*)d_ws;
  size_t used = 0;
  auto alloc = [&](size_t bytes) -> void* {
    void* p = (void*)wp;
    size_t a = (bytes + 255) & ~(size_t)255;
    wp += a; used += a;
    return p;
  };
  float* dinvw = (float*)alloc((size_t)NB * NN * 4);
  float* dinvu = (float*)alloc((size_t)NB * NN * 4);
  int*   indeg = (int*)alloc((size_t)NB * NN * 4);     // reused as fill
  int*   rowptr= (int*)alloc((size_t)NB * (NN + 1) * 4);
  int*   psrc  = (int*)alloc((size_t)NB * NE * 4);
  int*   pdst  = (int*)alloc((size_t)NB * NE * 4);
  float* pwn   = (float*)alloc((size_t)NB * NE * 4);
  float* pwu   = (float*)alloc((size_t)NB * NE * 4);
  float* lg    = (float*)alloc((size_t)NB * NE * NH * 4);
  float* lgs   = (float*)alloc((size_t)NB * NN * NH * 4);
  float* dden  = (float*)alloc((size_t)NB * NN * NH * 4);
  ushort* xbf  = (ushort*)alloc((size_t)M * 320 * 2);
  ushort* Wt1  = (ushort*)alloc((size_t)256 * 320 * 2);
  ushort* Wt2  = (ushort*)alloc((size_t)128 * 256 * 2);
  ushort* Wt3  = (ushort*)alloc((size_t)64 * 128 * 2);
  ushort* Wt4  = (ushort*)alloc((size_t)32 * 64 * 2);
  ushort* WtLR = (ushort*)alloc((size_t)256 * 32 * 2);
  ushort* Wtg1 = (ushort*)alloc((size_t)128 * 128 * 2);
  ushort* Wtm  = (ushort*)alloc((size_t)256 * 128 * 2);
  ushort* Wtg2 = (ushort*)alloc((size_t)256 * 256 * 2);
  ushort* B1 = (ushort*)alloc((size_t)M * 256 * 2);   // h1
  ushort* B2 = (ushort*)alloc((size_t)M * 256 * 2);
  ushort* B3 = (ushort*)alloc((size_t)M * 256 * 2);
  ushort* B4 = (ushort*)alloc((size_t)M * 256 * 2);   // xlr
  ushort* B2a = B2, *B2b = B2 + (size_t)M * 128;
  ushort* B3a = B3, *B3b = B3 + (size_t)M * 128;

  if (used > ws_size) {
    zero_out_k<<<(out_size + 255) / 256, 256, 0, stream>>>(out, out_size);
    return;
  }

  // ---- CSR + norms (packed) ----
  init_deg_k<<<NB * NN / 256, 256, 0, stream>>>(dinvw, indeg);
  accum_deg_k<<<NB * NE / 256, 256, 0, stream>>>(ei, ew, dinvw, indeg);
  finish_dinv_k<<<NB * NN / 256, 256, 0, stream>>>(dinvw, indeg, dinvu);
  scan_k<<<NB, NN, 0, stream>>>(indeg, rowptr, indeg);
  scatter_k<<<NB * NE / 256, 256, 0, stream>>>(ei, ew, dinvw, dinvu, indeg, rowptr,
                                               psrc, pdst, pwn, pwu);

  // ---- conversions ----
  xconv_k<<<(int)((size_t)M * 320 / 256), 256, 0, stream>>>(x, xbf);
  wconv_k<<<(256 * 320 + 255) / 256, 256, 0, stream>>>(W1, Wt1, 300, 256, 320);
  wconv_k<<<(128 * 256 + 255) / 256, 256, 0, stream>>>(W2, Wt2, 256, 128, 256);
  wconv_k<<<(64 * 128 + 255) / 256, 256, 0, stream>>>(W3, Wt3, 128, 64, 128);
  wconv_k<<<(32 * 64 + 255) / 256, 256, 0, stream>>>(W4, Wt4, 64, 32, 64);
  wconv_k<<<(128 * 32 + 255) / 256, 256, 0, stream>>>(Wl, WtLR, 32, 128, 32);
  wconv_k<<<(128 * 32 + 255) / 256, 256, 0, stream>>>(Wr, WtLR + 128 * 32, 32, 128, 32);
  wconv_k<<<(128 * 128 + 255) / 256, 256, 0, stream>>>(Wg1, Wtg1, 128, 128, 128);
  wconv_k<<<(256 * 128 + 255) / 256, 256, 0, stream>>>(Wm, Wtm, 128, 256, 128);
  wconv_k<<<(256 * 256 + 255) / 256, 256, 0, stream>>>(Wg2, Wtg2, 256, 256, 256);

  // ---- GCN stack ----
  mgemm_k<4,0><<<dim3(2, M / 128), 256, 0, stream>>>(xbf, Wt1, nullptr, B2, M, 320, 256);
  prop_k<256,0><<<M / 8, 256, 0, stream>>>(B2, B1, psrc, pwn, dinvw, rowptr, b1, nullptr);    // h1
  mgemm_k<4,0><<<dim3(1, M / 128), 256, 0, stream>>>(B1, Wt2, nullptr, B2a, M, 256, 128);
  prop_k<128,0><<<M / 16, 256, 0, stream>>>(B2a, B3a, psrc, pwn, dinvw, rowptr, b2, nullptr); // h2
  mgemm_k<2,0><<<dim3(1, M / 128), 256, 0, stream>>>(B3a, Wt3, nullptr, B2a, M, 128, 64);
  prop_k<64,0><<<M / 32, 256, 0, stream>>>(B2a, B3b, psrc, pwn, dinvw, rowptr, b3, nullptr);  // h3
  mgemm_k<1,0><<<dim3(1, M / 128), 256, 0, stream>>>(B3b, Wt4, nullptr, B2a, M, 64, 32);
  prop_k<32,0><<<M / 64, 256, 0, stream>>>(B2a, B2b, psrc, pwn, dinvw, rowptr, b4, nullptr);  // h4

  // ---- GATv2 (xl|xr in one GEMM; packed logits; alpha; gather) ----
  mgemm_k<4,0><<<dim3(2, M / 128), 256, 0, stream>>>(B2b, WtLR, nullptr, B4, M, 32, 256);     // xlr
  gat_logits_k<<<NB * ((NE + NN) * NH / 256), 256, 0, stream>>>(B4, psrc, pdst, att, lg, lgs);
  gat_alpha_k<<<NB * (NN / 256), 256, 0, stream>>>(lg, lgs, rowptr, dden);
  gat_gather_k<<<M / 16, 256, 0, stream>>>(B4, lg, lgs, dden, psrc, rowptr, bg, B2a);         // hg

  // ---- GCN2Conv #1 (x0 = h2 = B3a) ----
  prop_k<128,1><<<M / 16, 256, 0, stream>>>(B2a, B2b, psrc, pwn, dinvw, rowptr, nullptr, B3a); // z1
  mgemm_k<4,2><<<dim3(1, M / 128), 256, 0, stream>>>(B2b, Wtg1, B2b, B2a, M, 128, 128);       // h5

  // ---- GCNConv mid (unweighted norm) ----
  mgemm_k<4,0><<<dim3(2, M / 128), 256, 0, stream>>>(B2a, Wtm, nullptr, B3, M, 128, 256);
  prop_k<256,0><<<M / 8, 256, 0, stream>>>(B3, B2, psrc, pwu, dinvu, rowptr, bm, nullptr);    // h6

  // ---- GCN2Conv #2 (x0 = h1 = B1) ----
  prop_k<256,1><<<M / 8, 256, 0, stream>>>(B2, B3, psrc, pwn, dinvw, rowptr, nullptr, B1);    // z2
  mgemm_k<4,2><<<dim3(2, M / 128), 256, 0, stream>>>(B3, Wtg2, B3, B2, M, 256, 256);          // h7

  // ---- collapsed diff-pool + output projection ----
  pool_out_k<<<NB, 256, 0, stream>>>(B2, Wo, bo, out);
}

// Round 5
// 618.293 us; speedup vs baseline: 5.4754x; 1.2273x over previous
//
#include <hip/hip_runtime.h>
#include <cstdint>
#include <cstddef>

constexpr int NB = 64;     // graphs
constexpr int NN = 1024;   // nodes/graph
constexpr int NE = 16384;  // edges/graph
constexpr int NH = 4;      // GAT heads
constexpr float C_BETA = 0.04879016417f;   // log(0.1/2 + 1)

typedef __attribute__((ext_vector_type(8))) short s8v;   // 8 bf16 (4 VGPRs)
typedef __attribute__((ext_vector_type(4))) float f4v;

__device__ inline float bf2f(ushort u){ union{uint u;float f;} v; v.u=((uint)u)<<16; return v.f; }
__device__ inline ushort f2bf(float f){ union{float f;uint u;} v; v.f=f; uint r=v.u+0x7fffu+((v.u>>16)&1u); return (ushort)(r>>16); }
__device__ inline void up8(uint4 x, float* o){
  o[0]=bf2f((ushort)x.x); o[1]=bf2f((ushort)(x.x>>16));
  o[2]=bf2f((ushort)x.y); o[3]=bf2f((ushort)(x.y>>16));
  o[4]=bf2f((ushort)x.z); o[5]=bf2f((ushort)(x.z>>16));
  o[6]=bf2f((ushort)x.w); o[7]=bf2f((ushort)(x.w>>16));
}
__device__ inline uint pk2(float a, float b){ return (uint)f2bf(a) | ((uint)f2bf(b)<<16); }
__device__ inline uint4 pk8(const float* f){
  uint4 v; v.x=pk2(f[0],f[1]); v.y=pk2(f[2],f[3]); v.z=pk2(f[4],f[5]); v.w=pk2(f[6],f[7]); return v;
}
// XCD-bijective swizzle: graph g -> XCD g/(NB/8); requires grid = NB*bpg
__device__ inline int swz8(int bid, int bpg){
  int xcd = bid & 7, j = bid >> 3;
  return (xcd * (NB/8) + j / bpg) * bpg + (j % bpg);
}

// ---------------- degree / CSR build (+ fused edge-norm packing) ----------------

__global__ void init_deg_k(float* degw, int* indeg) {
  int g = blockIdx.x * 256 + threadIdx.x;
  degw[g] = 1.0f; indeg[g] = 0;
}

__global__ void accum_deg_k(const int* __restrict__ ei, const float* __restrict__ ew,
                            float* degw, int* indeg) {
  int g = blockIdx.x * 256 + threadIdx.x;
  int b = g / NE, e = g % NE;
  int d = ei[(size_t)b * 2 * NE + NE + e];
  atomicAdd(&degw[b * NN + d], ew[(size_t)b * NE + e]);
  atomicAdd(&indeg[b * NN + d], 1);
}

__global__ void finish_dinv_k(float* degw, const int* __restrict__ indeg, float* dinvu) {
  int g = blockIdx.x * 256 + threadIdx.x;
  degw[g] = rsqrtf(degw[g]);
  dinvu[g] = rsqrtf(1.0f + (float)indeg[g]);   // unweighted deg = count + self
}

__global__ __launch_bounds__(1024) void scan_k(const int* __restrict__ indeg,
                                               int* rowptr, int* fill) {
  int b = blockIdx.x, t = threadIdx.x;
  __shared__ int sb[NN];
  sb[t] = indeg[b * NN + t];
  __syncthreads();
  for (int off = 1; off < NN; off <<= 1) {
    int x = (t >= off) ? sb[t - off] : 0;
    __syncthreads();
    sb[t] += x;
    __syncthreads();
  }
  rowptr[b * (NN + 1) + t + 1] = sb[t];
  if (t == 0) rowptr[b * (NN + 1)] = 0;
  fill[b * NN + t] = 0;
}

// scatter + edge-norm fused: packed per-dst arrays (src, w_norm, w_unnorm)
__global__ void scatter_k(const int* __restrict__ ei, const float* __restrict__ ew,
                          const float* __restrict__ dw, const float* __restrict__ du,
                          int* fill, const int* __restrict__ rowptr,
                          int* psrc, float* pwn, float* pwu) {
  int g = blockIdx.x * 256 + threadIdx.x;
  int b = g / NE, e = g % NE;
  int s = ei[(size_t)b * 2 * NE + e];
  int d = ei[(size_t)b * 2 * NE + NE + e];
  int pos = rowptr[b * (NN + 1) + d] + atomicAdd(&fill[b * NN + d], 1);
  size_t o = (size_t)b * NE + pos;
  psrc[o] = s;
  pwn[o]  = dw[b * NN + s] * ew[(size_t)b * NE + e] * dw[b * NN + d];
  pwu[o]  = du[b * NN + s] * du[b * NN + d];
}

// ---------------- conversions ----------------

__global__ void xconv_k(const float* __restrict__ x, ushort* __restrict__ xbf) {
  int g = blockIdx.x * 256 + threadIdx.x;   // M*320
  int row = g / 320, c = g % 320;
  xbf[g] = (c < 300) ? f2bf(x[(size_t)row * 300 + c]) : (ushort)0;
}

__global__ void wconv_k(const float* __restrict__ W, ushort* __restrict__ Wt,
                        int K, int N, int Kp) {
  int g = blockIdx.x * 256 + threadIdx.x;
  if (g >= N * Kp) return;
  int n = g / Kp, k = g % Kp;
  Wt[g] = (k < K) ? f2bf(W[(size_t)k * N + n]) : (ushort)0;
}

// ---------------- MFMA bf16 GEMM: C[M,N] = A[M,K] @ W[K,N]  (Wt = W^T bf16) ----------------
// MODE 0: C = acc (bf16).  MODE 2: C = relu((1-beta)*Z + beta*acc) (GCN2 epilogue).

template<int NI, int MODE>
__global__ __launch_bounds__(256) void mgemm_k(const ushort* __restrict__ A,
    const ushort* __restrict__ Bt, const ushort* __restrict__ Z,
    ushort* __restrict__ C, int M, int K, int N) {
  constexpr int BN = NI * 32;
  __shared__ ushort As[128][40];   // pad to 80B rows: 2-way-free bank pattern
  __shared__ ushort Bs[BN][40];
  int tid = threadIdx.x;
  int wave = tid >> 6, lane = tid & 63;
  int bm = blockIdx.y * 128, bn = blockIdx.x * BN;
  int wm = (wave >> 1) * 64, wn = (wave & 1) * (NI * 16);
  f4v acc[4][NI];
#pragma unroll
  for (int a = 0; a < 4; ++a)
#pragma unroll
    for (int b = 0; b < NI; ++b)
#pragma unroll
      for (int q = 0; q < 4; ++q) acc[a][b][q] = 0.f;
  int r = lane & 15, kg = (lane >> 4) * 8;
  for (int k0 = 0; k0 < K; k0 += 32) {
#pragma unroll
    for (int c = tid; c < 512; c += 256) {
      int row = c >> 2, kc = (c & 3) * 8;
      *(uint4*)&As[row][kc] = *(const uint4*)&A[(size_t)(bm + row) * K + k0 + kc];
    }
#pragma unroll
    for (int c = tid; c < BN * 4; c += 256) {
      int col = c >> 2, kc = (c & 3) * 8;
      *(uint4*)&Bs[col][kc] = *(const uint4*)&Bt[(size_t)(bn + col) * K + k0 + kc];
    }
    __syncthreads();
    s8v af[4], bf[NI];
#pragma unroll
    for (int mi = 0; mi < 4; ++mi) af[mi] = *(const s8v*)&As[wm + mi * 16 + r][kg];
#pragma unroll
    for (int ni = 0; ni < NI; ++ni) bf[ni] = *(const s8v*)&Bs[wn + ni * 16 + r][kg];
#pragma unroll
    for (int mi = 0; mi < 4; ++mi)
#pragma unroll
      for (int ni = 0; ni < NI; ++ni)
        acc[mi][ni] = __builtin_amdgcn_mfma_f32_16x16x32_bf16(af[mi], bf[ni], acc[mi][ni], 0, 0, 0);
    __syncthreads();
  }
  int col = lane & 15, rowg = (lane >> 4) * 4;
#pragma unroll
  for (int mi = 0; mi < 4; ++mi)
#pragma unroll
    for (int ni = 0; ni < NI; ++ni)
#pragma unroll
      for (int q = 0; q < 4; ++q) {
        int row = bm + wm + mi * 16 + rowg + q;
        int cc = bn + wn + ni * 16 + col;
        size_t idx = (size_t)row * N + cc;
        float v = acc[mi][ni][q];
        if (MODE == 2) v = fmaxf((1.f - C_BETA) * bf2f(Z[idx]) + C_BETA * v, 0.f);
        C[idx] = f2bf(v);
      }
}

// ---------------- graph propagation (packed dst-CSR gather, bf16 I/O) ----------------
// acc = dinv[i]^2*in[i,:] + sum_p pw[p]*in[psrc[p],:]
// MODE 0: out = relu(acc + bias).  MODE 1: out = 0.5*acc + 0.5*x0.

template<int D, int MODE>
__global__ __launch_bounds__(256) void prop_k(const ushort* __restrict__ in,
    ushort* __restrict__ out, const int* __restrict__ psrc,
    const float* __restrict__ pw, const float* __restrict__ dinv,
    const int* __restrict__ rowptr, const float* __restrict__ bias,
    const ushort* __restrict__ x0) {
  constexpr int TPN = D / 8, NPB = 256 / TPN, BPG = NN / NPB;
  int t = threadIdx.x;
  int bid = swz8(blockIdx.x, BPG);
  int tn = t / TPN, cl = t % TPN;
  int node = bid * NPB + tn;
  int b = node >> 10, i = node & 1023;
  float di = dinv[node];
  float f[8], acc[8];
  uint4 ov = *(const uint4*)&in[(size_t)node * D + cl * 8];
  up8(ov, f);
  float w0 = di * di;
#pragma unroll
  for (int j = 0; j < 8; ++j) acc[j] = w0 * f[j];
  int r0 = rowptr[b * (NN + 1) + i], r1 = rowptr[b * (NN + 1) + i + 1];
  const int* ps = psrc + (size_t)b * NE;
  const float* pwb = pw + (size_t)b * NE;
  const ushort* inb = in + (size_t)b * NN * D;
  int p = r0;
  for (; p + 4 <= r1; p += 4) {      // 4-way unroll: independent loads
    int s0 = ps[p], s1 = ps[p + 1], s2 = ps[p + 2], s3 = ps[p + 3];
    float wa = pwb[p], wb2 = pwb[p + 1], wc = pwb[p + 2], wd = pwb[p + 3];
    uint4 rv0 = *(const uint4*)&inb[(size_t)s0 * D + cl * 8];
    uint4 rv1 = *(const uint4*)&inb[(size_t)s1 * D + cl * 8];
    uint4 rv2 = *(const uint4*)&inb[(size_t)s2 * D + cl * 8];
    uint4 rv3 = *(const uint4*)&inb[(size_t)s3 * D + cl * 8];
    up8(rv0, f);
#pragma unroll
    for (int j = 0; j < 8; ++j) acc[j] += wa * f[j];
    up8(rv1, f);
#pragma unroll
    for (int j = 0; j < 8; ++j) acc[j] += wb2 * f[j];
    up8(rv2, f);
#pragma unroll
    for (int j = 0; j < 8; ++j) acc[j] += wc * f[j];
    up8(rv3, f);
#pragma unroll
    for (int j = 0; j < 8; ++j) acc[j] += wd * f[j];
  }
  for (; p < r1; ++p) {
    int s = ps[p]; float w = pwb[p];
    uint4 rv = *(const uint4*)&inb[(size_t)s * D + cl * 8];
    up8(rv, f);
#pragma unroll
    for (int j = 0; j < 8; ++j) acc[j] += w * f[j];
  }
  size_t ob = (size_t)node * D + cl * 8;
  if (MODE == 0) {
#pragma unroll
    for (int j = 0; j < 8; ++j) acc[j] = fmaxf(acc[j] + bias[cl * 8 + j], 0.f);
  } else {
    uint4 xv = *(const uint4*)&x0[ob];
    up8(xv, f);
#pragma unroll
    for (int j = 0; j < 8; ++j) acc[j] = 0.5f * acc[j] + 0.5f * f[j];
  }
  *(uint4*)&out[ob] = pk8(acc);
}

// ---------------- GATv2: fused flash-style (logit + online softmax + gather) ----------------
// xlr layout: [node][256]: ch 0-127 = xl, 128-255 = xr.
// 16 thr/node x 8 ch; head h = cl>>2; logit = 4-lane shfl reduce of
// att . leaky_relu(xl[s] + xr[i]); online m/den/acc update; value IS xl[s].

__global__ __launch_bounds__(256) void gat_fused_k(const ushort* __restrict__ xlr,
    const int* __restrict__ psrc, const int* __restrict__ rowptr,
    const float* __restrict__ att, const float* __restrict__ bg,
    ushort* __restrict__ out) {
  int bid = swz8(blockIdx.x, NN / 16);   // 16 nodes/block
  int t = threadIdx.x;
  int tn = t >> 4, cl = t & 15;
  int node = bid * 16 + tn;
  int b = node >> 10, i = node & 1023;
  int ch = cl * 8;
  int r0 = rowptr[b * (NN + 1) + i], r1 = rowptr[b * (NN + 1) + i + 1];
  const ushort* xb = xlr + (size_t)b * NN * 256;
  const int* ps = psrc + (size_t)b * NE;
  float fr[8], at[8];
  {
    uint4 rv = *(const uint4*)&xb[(size_t)i * 256 + 128 + ch];  // xr[i] chunk
    up8(rv, fr);
#pragma unroll
    for (int j = 0; j < 8; ++j) at[j] = att[ch + j];   // flat att == ch+j
  }
  float m, den, acc[8];
  {
    float fs[8];
    uint4 sv = *(const uint4*)&xb[(size_t)i * 256 + ch];        // xl[i] (self)
    up8(sv, fs);
    float part = 0.f;
#pragma unroll
    for (int j = 0; j < 8; ++j) {
      float v = fs[j] + fr[j];
      v = v > 0.f ? v : 0.2f * v;
      part += v * at[j];
    }
    part += __shfl_xor(part, 1);
    part += __shfl_xor(part, 2);
    m = part; den = 1.f;
#pragma unroll
    for (int j = 0; j < 8; ++j) acc[j] = fs[j];
  }
  float fl0[8], fl1[8];
  int p = r0;
  for (; p + 2 <= r1; p += 2) {
    int s0 = ps[p], s1 = ps[p + 1];
    uint4 v0 = *(const uint4*)&xb[(size_t)s0 * 256 + ch];
    uint4 v1 = *(const uint4*)&xb[(size_t)s1 * 256 + ch];
    up8(v0, fl0); up8(v1, fl1);
    float p0 = 0.f, p1 = 0.f;
#pragma unroll
    for (int j = 0; j < 8; ++j) {
      float a0 = fl0[j] + fr[j]; a0 = a0 > 0.f ? a0 : 0.2f * a0;
      float a1 = fl1[j] + fr[j]; a1 = a1 > 0.f ? a1 : 0.2f * a1;
      p0 += a0 * at[j]; p1 += a1 * at[j];
    }
    p0 += __shfl_xor(p0, 1); p0 += __shfl_xor(p0, 2);
    p1 += __shfl_xor(p1, 1); p1 += __shfl_xor(p1, 2);
    {
      float mn = fmaxf(m, p0);
      float sc = __expf(m - mn), ex = __expf(p0 - mn);
      den = den * sc + ex;
#pragma unroll
      for (int j = 0; j < 8; ++j) acc[j] = acc[j] * sc + ex * fl0[j];
      m = mn;
    }
    {
      float mn = fmaxf(m, p1);
      float sc = __expf(m - mn), ex = __expf(p1 - mn);
      den = den * sc + ex;
#pragma unroll
      for (int j = 0; j < 8; ++j) acc[j] = acc[j] * sc + ex * fl1[j];
      m = mn;
    }
  }
  if (p < r1) {
    int s = ps[p];
    uint4 v0 = *(const uint4*)&xb[(size_t)s * 256 + ch];
    up8(v0, fl0);
    float p0 = 0.f;
#pragma unroll
    for (int j = 0; j < 8; ++j) {
      float a0 = fl0[j] + fr[j]; a0 = a0 > 0.f ? a0 : 0.2f * a0;
      p0 += a0 * at[j];
    }
    p0 += __shfl_xor(p0, 1); p0 += __shfl_xor(p0, 2);
    float mn = fmaxf(m, p0);
    float sc = __expf(m - mn), ex = __expf(p0 - mn);
    den = den * sc + ex;
#pragma unroll
    for (int j = 0; j < 8; ++j) acc[j] = acc[j] * sc + ex * fl0[j];
    m = mn;
  }
  float inv = 1.f / den;
#pragma unroll
  for (int j = 0; j < 8; ++j) acc[j] = fmaxf(acc[j] * inv + bg[ch + j], 0.f);
  *(uint4*)&out[(size_t)node * 128 + ch] = pk8(acc);
}

// ---------------- pooled = column-sum(h7); out = pooled @ Wo + bo ----------------
// (diff-pool tail collapses: softmax over size-1 axis == 1; assignment rows sum to 1.)

__global__ __launch_bounds__(256) void pool_out_k(const ushort* __restrict__ h7,
    const float* __restrict__ Wo, const float* __restrict__ bo, float* __restrict__ out) {
  int bgr = blockIdx.x, t = threadIdx.x;
  int rg = t >> 5, cl = t & 31;   // 8 row-groups x 32 chunk-lanes
  const ushort* hb = h7 + (size_t)bgr * NN * 256;
  float a[8] = {};
  float f[8];
  for (int r = rg; r < NN; r += 8) {
    uint4 v = *(const uint4*)&hb[(size_t)r * 256 + cl * 8];
    up8(v, f);
#pragma unroll
    for (int j = 0; j < 8; ++j) a[j] += f[j];
  }
  __shared__ float red[8][256];
#pragma unroll
  for (int j = 0; j < 8; ++j) red[rg][cl * 8 + j] = a[j];
  __syncthreads();
  float pooled = 0.f;
#pragma unroll
  for (int g = 0; g < 8; ++g) pooled += red[g][t];
  __shared__ float pv[256];
  pv[t] = pooled;
  __syncthreads();
  if (t < 8) {
    float o = bo[t];
    for (int c = 0; c < 256; ++c) o += pv[c] * Wo[c * 8 + t];
    out[bgr * 8 + t] = o;
  }
}

__global__ void zero_out_k(float* out, int n) {
  int g = blockIdx.x * 256 + threadIdx.x;
  if (g < n) out[g] = 0.f;
}

// ---------------- launch ----------------

extern "C" void kernel_launch(void* const* d_in, const int* in_sizes, int n_in,
                              void* d_out, int out_size, void* d_ws, size_t ws_size,
                              hipStream_t stream) {
  const float* x   = (const float*)d_in[0];
  const int*   ei  = (const int*)d_in[1];
  const float* ew  = (const float*)d_in[2];
  const float* W1  = (const float*)d_in[3];
  const float* b1  = (const float*)d_in[4];
  const float* W2  = (const float*)d_in[5];
  const float* b2  = (const float*)d_in[6];
  const float* W3  = (const float*)d_in[7];
  const float* b3  = (const float*)d_in[8];
  const float* W4  = (const float*)d_in[9];
  const float* b4  = (const float*)d_in[10];
  const float* Wl  = (const float*)d_in[11];
  const float* Wr  = (const float*)d_in[12];
  const float* att = (const float*)d_in[13];
  const float* bg  = (const float*)d_in[14];
  const float* Wg1 = (const float*)d_in[15];
  const float* Wm  = (const float*)d_in[16];
  const float* bm  = (const float*)d_in[17];
  const float* Wg2 = (const float*)d_in[18];
  const float* Wo  = (const float*)d_in[23];
  const float* bo  = (const float*)d_in[24];
  float* out = (float*)d_out;

  const int M = NB * NN;

  char* wp = (char*)d_ws;
  size_t used = 0;
  auto alloc = [&](size_t bytes) -> void* {
    void* p = (void*)wp;
    size_t a = (bytes + 255) & ~(size_t)255;
    wp += a; used += a;
    return p;
  };
  float* dinvw = (float*)alloc((size_t)NB * NN * 4);
  float* dinvu = (float*)alloc((size_t)NB * NN * 4);
  int*   indeg = (int*)alloc((size_t)NB * NN * 4);     // reused as fill
  int*   rowptr= (int*)alloc((size_t)NB * (NN + 1) * 4);
  int*   psrc  = (int*)alloc((size_t)NB * NE * 4);
  float* pwn   = (float*)alloc((size_t)NB * NE * 4);
  float* pwu   = (float*)alloc((size_t)NB * NE * 4);
  ushort* xbf  = (ushort*)alloc((size_t)M * 320 * 2);
  ushort* Wt1  = (ushort*)alloc((size_t)256 * 320 * 2);
  ushort* Wt2  = (ushort*)alloc((size_t)128 * 256 * 2);
  ushort* Wt3  = (ushort*)alloc((size_t)64 * 128 * 2);
  ushort* Wt4  = (ushort*)alloc((size_t)32 * 64 * 2);
  ushort* WtLR = (ushort*)alloc((size_t)256 * 32 * 2);
  ushort* Wtg1 = (ushort*)alloc((size_t)128 * 128 * 2);
  ushort* Wtm  = (ushort*)alloc((size_t)256 * 128 * 2);
  ushort* Wtg2 = (ushort*)alloc((size_t)256 * 256 * 2);
  ushort* B1 = (ushort*)alloc((size_t)M * 256 * 2);   // h1
  ushort* B2 = (ushort*)alloc((size_t)M * 256 * 2);
  ushort* B3 = (ushort*)alloc((size_t)M * 256 * 2);
  ushort* B4 = (ushort*)alloc((size_t)M * 256 * 2);   // xlr
  ushort* B2a = B2, *B2b = B2 + (size_t)M * 128;
  ushort* B3a = B3, *B3b = B3 + (size_t)M * 128;

  if (used > ws_size) {
    zero_out_k<<<(out_size + 255) / 256, 256, 0, stream>>>(out, out_size);
    return;
  }

  // ---- CSR + norms (packed) ----
  init_deg_k<<<NB * NN / 256, 256, 0, stream>>>(dinvw, indeg);
  accum_deg_k<<<NB * NE / 256, 256, 0, stream>>>(ei, ew, dinvw, indeg);
  finish_dinv_k<<<NB * NN / 256, 256, 0, stream>>>(dinvw, indeg, dinvu);
  scan_k<<<NB, NN, 0, stream>>>(indeg, rowptr, indeg);
  scatter_k<<<NB * NE / 256, 256, 0, stream>>>(ei, ew, dinvw, dinvu, indeg, rowptr,
                                               psrc, pwn, pwu);

  // ---- conversions ----
  xconv_k<<<(int)((size_t)M * 320 / 256), 256, 0, stream>>>(x, xbf);
  wconv_k<<<(256 * 320 + 255) / 256, 256, 0, stream>>>(W1, Wt1, 300, 256, 320);
  wconv_k<<<(128 * 256 + 255) / 256, 256, 0, stream>>>(W2, Wt2, 256, 128, 256);
  wconv_k<<<(64 * 128 + 255) / 256, 256, 0, stream>>>(W3, Wt3, 128, 64, 128);
  wconv_k<<<(32 * 64 + 255) / 256, 256, 0, stream>>>(W4, Wt4, 64, 32, 64);
  wconv_k<<<(128 * 32 + 255) / 256, 256, 0, stream>>>(Wl, WtLR, 32, 128, 32);
  wconv_k<<<(128 * 32 + 255) / 256, 256, 0, stream>>>(Wr, WtLR + 128 * 32, 32, 128, 32);
  wconv_k<<<(128 * 128 + 255) / 256, 256, 0, stream>>>(Wg1, Wtg1, 128, 128, 128);
  wconv_k<<<(256 * 128 + 255) / 256, 256, 0, stream>>>(Wm, Wtm, 128, 256, 128);
  wconv_k<<<(256 * 256 + 255) / 256, 256, 0, stream>>>(Wg2, Wtg2, 256, 256, 256);

  // ---- GCN stack ----
  mgemm_k<4,0><<<dim3(2, M / 128), 256, 0, stream>>>(xbf, Wt1, nullptr, B2, M, 320, 256);
  prop_k<256,0><<<M / 8, 256, 0, stream>>>(B2, B1, psrc, pwn, dinvw, rowptr, b1, nullptr);    // h1
  mgemm_k<4,0><<<dim3(1, M / 128), 256, 0, stream>>>(B1, Wt2, nullptr, B2a, M, 256, 128);
  prop_k<128,0><<<M / 16, 256, 0, stream>>>(B2a, B3a, psrc, pwn, dinvw, rowptr, b2, nullptr); // h2
  mgemm_k<2,0><<<dim3(1, M / 128), 256, 0, stream>>>(B3a, Wt3, nullptr, B2a, M, 128, 64);
  prop_k<64,0><<<M / 32, 256, 0, stream>>>(B2a, B3b, psrc, pwn, dinvw, rowptr, b3, nullptr);  // h3
  mgemm_k<1,0><<<dim3(1, M / 128), 256, 0, stream>>>(B3b, Wt4, nullptr, B2a, M, 64, 32);
  prop_k<32,0><<<M / 64, 256, 0, stream>>>(B2a, B2b, psrc, pwn, dinvw, rowptr, b4, nullptr);  // h4

  // ---- GATv2 (xl|xr one GEMM; fused flash-style attention) ----
  mgemm_k<4,0><<<dim3(2, M / 128), 256, 0, stream>>>(B2b, WtLR, nullptr, B4, M, 32, 256);     // xlr
  gat_fused_k<<<M / 16, 256, 0, stream>>>(B4, psrc, rowptr, att, bg, B2a);                    // hg

  // ---- GCN2Conv #1 (x0 = h2 = B3a) ----
  prop_k<128,1><<<M / 16, 256, 0, stream>>>(B2a, B2b, psrc, pwn, dinvw, rowptr, nullptr, B3a); // z1
  mgemm_k<4,2><<<dim3(1, M / 128), 256, 0, stream>>>(B2b, Wtg1, B2b, B2a, M, 128, 128);       // h5

  // ---- GCNConv mid (unweighted norm) ----
  mgemm_k<4,0><<<dim3(2, M / 128), 256, 0, stream>>>(B2a, Wtm, nullptr, B3, M, 128, 256);
  prop_k<256,0><<<M / 8, 256, 0, stream>>>(B3, B2, psrc, pwu, dinvu, rowptr, bm, nullptr);    // h6

  // ---- GCN2Conv #2 (x0 = h1 = B1) ----
  prop_k<256,1><<<M / 8, 256, 0, stream>>>(B2, B3, psrc, pwn, dinvw, rowptr, nullptr, B1);    // z2
  mgemm_k<4,2><<<dim3(2, M / 128), 256, 0, stream>>>(B3, Wtg2, B3, B2, M, 256, 256);          // h7

  // ---- collapsed diff-pool + output projection ----
  pool_out_k<<<NB, 256, 0, stream>>>(B2, Wo, bo, out);
}

// Round 6
// 534.729 us; speedup vs baseline: 6.3311x; 1.1563x over previous
//
#include <hip/hip_runtime.h>
#include <cstdint>
#include <cstddef>

constexpr int NB = 64;     // graphs
constexpr int NN = 1024;   // nodes/graph
constexpr int NE = 16384;  // edges/graph
constexpr float C_BETA = 0.04879016417f;   // log(0.1/2 + 1)

typedef __attribute__((ext_vector_type(8))) short s8v;   // 8 bf16 (4 VGPRs)
typedef __attribute__((ext_vector_type(4))) float f4v;

__device__ inline float bf2f(ushort u){ union{uint u;float f;} v; v.u=((uint)u)<<16; return v.f; }
__device__ inline ushort f2bf(float f){ union{float f;uint u;} v; v.f=f; uint r=v.u+0x7fffu+((v.u>>16)&1u); return (ushort)(r>>16); }
__device__ inline void up8(uint4 x, float* o){
  o[0]=bf2f((ushort)x.x); o[1]=bf2f((ushort)(x.x>>16));
  o[2]=bf2f((ushort)x.y); o[3]=bf2f((ushort)(x.y>>16));
  o[4]=bf2f((ushort)x.z); o[5]=bf2f((ushort)(x.z>>16));
  o[6]=bf2f((ushort)x.w); o[7]=bf2f((ushort)(x.w>>16));
}
__device__ inline uint pk2(float a, float b){ return (uint)f2bf(a) | ((uint)f2bf(b)<<16); }
__device__ inline uint4 pk8(const float* f){
  uint4 v; v.x=pk2(f[0],f[1]); v.y=pk2(f[2],f[3]); v.z=pk2(f[4],f[5]); v.w=pk2(f[6],f[7]); return v;
}
// XCD-bijective swizzle: graph g -> XCD g/(NB/8); requires grid = NB*bpg
__device__ inline int swz8(int bid, int bpg){
  int xcd = bid & 7, j = bid >> 3;
  return (xcd * (NB/8) + j / bpg) * bpg + (j % bpg);
}

// ---------------- fused per-graph CSR build ----------------
// One block (1024 thr) per graph: LDS histogram + weighted degree, dinv,
// Hillis-Steele scan, scatter fill. Replaces init/accum/finish/scan/scatter.

__global__ __launch_bounds__(1024) void build_csr_k(
    const int* __restrict__ ei, const float* __restrict__ ew,
    float* __restrict__ dinvw_g, float* __restrict__ dinvu_g,
    int* __restrict__ rowptr_g, int* __restrict__ psrc,
    float* __restrict__ pwn, float* __restrict__ pwu) {
  int b = blockIdx.x, t = threadIdx.x;
  __shared__ float sdegw[NN];
  __shared__ int   scnt[NN];
  __shared__ float sdw[NN];
  __shared__ float sdu[NN];
  __shared__ int   sscan[NN];
  sdegw[t] = 1.0f;   // self loop weight
  scnt[t] = 0;
  __syncthreads();
  const int* srcb = ei + (size_t)b * 2 * NE;
  const int* dstb = srcb + NE;
  const float* ewb = ew + (size_t)b * NE;
  for (int e = t; e < NE; e += 1024) {
    int d = dstb[e];
    atomicAdd(&sdegw[d], ewb[e]);
    atomicAdd(&scnt[d], 1);
  }
  __syncthreads();
  float dw = rsqrtf(sdegw[t]);
  float du = rsqrtf(1.0f + (float)scnt[t]);
  sdw[t] = dw; sdu[t] = du;
  dinvw_g[b * NN + t] = dw;
  dinvu_g[b * NN + t] = du;
  sscan[t] = scnt[t];
  __syncthreads();
  for (int off = 1; off < NN; off <<= 1) {
    int xv = (t >= off) ? sscan[t - off] : 0;
    __syncthreads();
    sscan[t] += xv;
    __syncthreads();
  }
  rowptr_g[b * (NN + 1) + t + 1] = sscan[t];
  if (t == 0) rowptr_g[b * (NN + 1)] = 0;
  sscan[t] -= scnt[t];      // exclusive prefix
  scnt[t] = 0;              // reuse as fill counter
  __syncthreads();
  for (int e = t; e < NE; e += 1024) {
    int s = srcb[e], d = dstb[e];
    int pos = sscan[d] + atomicAdd(&scnt[d], 1);
    size_t o = (size_t)b * NE + pos;
    psrc[o] = s;
    pwn[o]  = sdw[s] * ewb[e] * sdw[d];
    pwu[o]  = sdu[s] * sdu[d];
  }
}

// ---------------- conversions ----------------

__global__ void xconv_k(const float* __restrict__ x, ushort* __restrict__ xbf) {
  int g = blockIdx.x * 256 + threadIdx.x;   // M*40 threads, 8 cols each
  int row = g / 40, c = (g % 40) * 8;
  float f[8];
  const float* xr = x + (size_t)row * 300;
  if (c + 8 <= 300) {
    float4 a = *(const float4*)&xr[c];
    float4 bq = *(const float4*)&xr[c + 4];
    f[0]=a.x; f[1]=a.y; f[2]=a.z; f[3]=a.w;
    f[4]=bq.x; f[5]=bq.y; f[6]=bq.z; f[7]=bq.w;
  } else {
#pragma unroll
    for (int j = 0; j < 8; ++j) f[j] = (c + j < 300) ? xr[c + j] : 0.f;
  }
  *(uint4*)&xbf[(size_t)row * 320 + c] = pk8(f);
}

__device__ inline void wcv(const float* __restrict__ W, ushort* __restrict__ Wt,
                           int idx, int K, int N, int Kp) {
  int n = idx / Kp, k = idx % Kp;
  Wt[idx] = (k < K) ? f2bf(W[(size_t)k * N + n]) : (ushort)0;
}

// all weight transposes in one launch (grid = 968 blocks x 256)
__global__ void wconv_all_k(const float* W1, const float* W2, const float* W3,
                            const float* W4, const float* Wl, const float* Wr,
                            const float* Wg1, const float* Wm, const float* Wg2,
                            ushort* Wt1, ushort* Wt2, ushort* Wt3, ushort* Wt4,
                            ushort* WtLR, ushort* Wtg1, ushort* Wtm, ushort* Wtg2) {
  int bb = blockIdx.x, t = threadIdx.x;
  if      (bb < 320) wcv(W1, Wt1, bb * 256 + t, 300, 256, 320);
  else if (bb < 448) wcv(W2, Wt2, (bb - 320) * 256 + t, 256, 128, 256);
  else if (bb < 480) wcv(W3, Wt3, (bb - 448) * 256 + t, 128, 64, 128);
  else if (bb < 488) wcv(W4, Wt4, (bb - 480) * 256 + t, 64, 32, 64);
  else if (bb < 504) wcv(Wl, WtLR, (bb - 488) * 256 + t, 32, 128, 32);
  else if (bb < 520) wcv(Wr, WtLR + 128 * 32, (bb - 504) * 256 + t, 32, 128, 32);
  else if (bb < 584) wcv(Wg1, Wtg1, (bb - 520) * 256 + t, 128, 128, 128);
  else if (bb < 712) wcv(Wm, Wtm, (bb - 584) * 256 + t, 128, 256, 128);
  else               wcv(Wg2, Wtg2, (bb - 712) * 256 + t, 256, 256, 256);
}

// ---------------- MFMA bf16 GEMM: C[M,N] = A[M,K] @ W[K,N]  (Wt = W^T bf16) ----------------
// MODE 0: C = acc (bf16).  MODE 2: C = relu((1-beta)*Z + beta*acc) (GCN2 epilogue).

template<int NI, int MODE>
__global__ __launch_bounds__(256) void mgemm_k(const ushort* __restrict__ A,
    const ushort* __restrict__ Bt, const ushort* __restrict__ Z,
    ushort* __restrict__ C, int M, int K, int N) {
  constexpr int BN = NI * 32;
  __shared__ ushort As[128][40];   // pad to 80B rows: 2-way-free bank pattern
  __shared__ ushort Bs[BN][40];
  int tid = threadIdx.x;
  int wave = tid >> 6, lane = tid & 63;
  int bm = blockIdx.y * 128, bn = blockIdx.x * BN;
  int wm = (wave >> 1) * 64, wn = (wave & 1) * (NI * 16);
  f4v acc[4][NI];
#pragma unroll
  for (int a = 0; a < 4; ++a)
#pragma unroll
    for (int b = 0; b < NI; ++b)
#pragma unroll
      for (int q = 0; q < 4; ++q) acc[a][b][q] = 0.f;
  int r = lane & 15, kg = (lane >> 4) * 8;
  for (int k0 = 0; k0 < K; k0 += 32) {
#pragma unroll
    for (int c = tid; c < 512; c += 256) {
      int row = c >> 2, kc = (c & 3) * 8;
      *(uint4*)&As[row][kc] = *(const uint4*)&A[(size_t)(bm + row) * K + k0 + kc];
    }
#pragma unroll
    for (int c = tid; c < BN * 4; c += 256) {
      int col = c >> 2, kc = (c & 3) * 8;
      *(uint4*)&Bs[col][kc] = *(const uint4*)&Bt[(size_t)(bn + col) * K + k0 + kc];
    }
    __syncthreads();
    s8v af[4], bf[NI];
#pragma unroll
    for (int mi = 0; mi < 4; ++mi) af[mi] = *(const s8v*)&As[wm + mi * 16 + r][kg];
#pragma unroll
    for (int ni = 0; ni < NI; ++ni) bf[ni] = *(const s8v*)&Bs[wn + ni * 16 + r][kg];
#pragma unroll
    for (int mi = 0; mi < 4; ++mi)
#pragma unroll
      for (int ni = 0; ni < NI; ++ni)
        acc[mi][ni] = __builtin_amdgcn_mfma_f32_16x16x32_bf16(af[mi], bf[ni], acc[mi][ni], 0, 0, 0);
    __syncthreads();
  }
  int col = lane & 15, rowg = (lane >> 4) * 4;
#pragma unroll
  for (int mi = 0; mi < 4; ++mi)
#pragma unroll
    for (int ni = 0; ni < NI; ++ni)
#pragma unroll
      for (int q = 0; q < 4; ++q) {
        int row = bm + wm + mi * 16 + rowg + q;
        int cc = bn + wn + ni * 16 + col;
        size_t idx = (size_t)row * N + cc;
        float v = acc[mi][ni][q];
        if (MODE == 2) v = fmaxf((1.f - C_BETA) * bf2f(Z[idx]) + C_BETA * v, 0.f);
        C[idx] = f2bf(v);
      }
}

// ---------------- graph propagation (packed dst-CSR gather, bf16 I/O) ----------------
// acc = dinv[i]^2*in[i,:] + sum_p pw[p]*in[psrc[p],:]
// MODE 0: out = relu(acc + bias).  MODE 1: out = 0.5*acc + 0.5*x0.

template<int D, int MODE>
__global__ __launch_bounds__(256) void prop_k(const ushort* __restrict__ in,
    ushort* __restrict__ out, const int* __restrict__ psrc,
    const float* __restrict__ pw, const float* __restrict__ dinv,
    const int* __restrict__ rowptr, const float* __restrict__ bias,
    const ushort* __restrict__ x0) {
  constexpr int TPN = D / 8, NPB = 256 / TPN, BPG = NN / NPB;
  int t = threadIdx.x;
  int bid = swz8(blockIdx.x, BPG);
  int tn = t / TPN, cl = t % TPN;
  int node = bid * NPB + tn;
  int b = node >> 10, i = node & 1023;
  float di = dinv[node];
  float f[8], acc[8];
  uint4 ov = *(const uint4*)&in[(size_t)node * D + cl * 8];
  up8(ov, f);
  float w0 = di * di;
#pragma unroll
  for (int j = 0; j < 8; ++j) acc[j] = w0 * f[j];
  int r0 = rowptr[b * (NN + 1) + i], r1 = rowptr[b * (NN + 1) + i + 1];
  const int* ps = psrc + (size_t)b * NE;
  const float* pwb = pw + (size_t)b * NE;
  const ushort* inb = in + (size_t)b * NN * D;
  int p = r0;
  for (; p + 4 <= r1; p += 4) {      // 4-way unroll: independent loads
    int s0 = ps[p], s1 = ps[p + 1], s2 = ps[p + 2], s3 = ps[p + 3];
    float wa = pwb[p], wb2 = pwb[p + 1], wc = pwb[p + 2], wd = pwb[p + 3];
    uint4 rv0 = *(const uint4*)&inb[(size_t)s0 * D + cl * 8];
    uint4 rv1 = *(const uint4*)&inb[(size_t)s1 * D + cl * 8];
    uint4 rv2 = *(const uint4*)&inb[(size_t)s2 * D + cl * 8];
    uint4 rv3 = *(const uint4*)&inb[(size_t)s3 * D + cl * 8];
    up8(rv0, f);
#pragma unroll
    for (int j = 0; j < 8; ++j) acc[j] += wa * f[j];
    up8(rv1, f);
#pragma unroll
    for (int j = 0; j < 8; ++j) acc[j] += wb2 * f[j];
    up8(rv2, f);
#pragma unroll
    for (int j = 0; j < 8; ++j) acc[j] += wc * f[j];
    up8(rv3, f);
#pragma unroll
    for (int j = 0; j < 8; ++j) acc[j] += wd * f[j];
  }
  for (; p < r1; ++p) {
    int s = ps[p]; float w = pwb[p];
    uint4 rv = *(const uint4*)&inb[(size_t)s * D + cl * 8];
    up8(rv, f);
#pragma unroll
    for (int j = 0; j < 8; ++j) acc[j] += w * f[j];
  }
  size_t ob = (size_t)node * D + cl * 8;
  if (MODE == 0) {
#pragma unroll
    for (int j = 0; j < 8; ++j) acc[j] = fmaxf(acc[j] + bias[cl * 8 + j], 0.f);
  } else {
    uint4 xv = *(const uint4*)&x0[ob];
    up8(xv, f);
#pragma unroll
    for (int j = 0; j < 8; ++j) acc[j] = 0.5f * acc[j] + 0.5f * f[j];
  }
  *(uint4*)&out[ob] = pk8(acc);
}

// ---------------- GATv2: fused flash-style (logit + online softmax + gather) ----------------
// xlr layout: [node][256]: ch 0-127 = xl, 128-255 = xr.

__global__ __launch_bounds__(256) void gat_fused_k(const ushort* __restrict__ xlr,
    const int* __restrict__ psrc, const int* __restrict__ rowptr,
    const float* __restrict__ att, const float* __restrict__ bg,
    ushort* __restrict__ out) {
  int bid = swz8(blockIdx.x, NN / 16);   // 16 nodes/block
  int t = threadIdx.x;
  int tn = t >> 4, cl = t & 15;
  int node = bid * 16 + tn;
  int b = node >> 10, i = node & 1023;
  int ch = cl * 8;
  int r0 = rowptr[b * (NN + 1) + i], r1 = rowptr[b * (NN + 1) + i + 1];
  const ushort* xb = xlr + (size_t)b * NN * 256;
  const int* ps = psrc + (size_t)b * NE;
  float fr[8], at[8];
  {
    uint4 rv = *(const uint4*)&xb[(size_t)i * 256 + 128 + ch];  // xr[i] chunk
    up8(rv, fr);
#pragma unroll
    for (int j = 0; j < 8; ++j) at[j] = att[ch + j];   // flat att == ch+j
  }
  float m, den, acc[8];
  {
    float fs[8];
    uint4 sv = *(const uint4*)&xb[(size_t)i * 256 + ch];        // xl[i] (self)
    up8(sv, fs);
    float part = 0.f;
#pragma unroll
    for (int j = 0; j < 8; ++j) {
      float v = fs[j] + fr[j];
      v = v > 0.f ? v : 0.2f * v;
      part += v * at[j];
    }
    part += __shfl_xor(part, 1);
    part += __shfl_xor(part, 2);
    m = part; den = 1.f;
#pragma unroll
    for (int j = 0; j < 8; ++j) acc[j] = fs[j];
  }
  float fl0[8], fl1[8];
  int p = r0;
  for (; p + 2 <= r1; p += 2) {
    int s0 = ps[p], s1 = ps[p + 1];
    uint4 v0 = *(const uint4*)&xb[(size_t)s0 * 256 + ch];
    uint4 v1 = *(const uint4*)&xb[(size_t)s1 * 256 + ch];
    up8(v0, fl0); up8(v1, fl1);
    float p0 = 0.f, p1 = 0.f;
#pragma unroll
    for (int j = 0; j < 8; ++j) {
      float a0 = fl0[j] + fr[j]; a0 = a0 > 0.f ? a0 : 0.2f * a0;
      float a1 = fl1[j] + fr[j]; a1 = a1 > 0.f ? a1 : 0.2f * a1;
      p0 += a0 * at[j]; p1 += a1 * at[j];
    }
    p0 += __shfl_xor(p0, 1); p0 += __shfl_xor(p0, 2);
    p1 += __shfl_xor(p1, 1); p1 += __shfl_xor(p1, 2);
    {
      float mn = fmaxf(m, p0);
      float sc = __expf(m - mn), ex = __expf(p0 - mn);
      den = den * sc + ex;
#pragma unroll
      for (int j = 0; j < 8; ++j) acc[j] = acc[j] * sc + ex * fl0[j];
      m = mn;
    }
    {
      float mn = fmaxf(m, p1);
      float sc = __expf(m - mn), ex = __expf(p1 - mn);
      den = den * sc + ex;
#pragma unroll
      for (int j = 0; j < 8; ++j) acc[j] = acc[j] * sc + ex * fl1[j];
      m = mn;
    }
  }
  if (p < r1) {
    int s = ps[p];
    uint4 v0 = *(const uint4*)&xb[(size_t)s * 256 + ch];
    up8(v0, fl0);
    float p0 = 0.f;
#pragma unroll
    for (int j = 0; j < 8; ++j) {
      float a0 = fl0[j] + fr[j]; a0 = a0 > 0.f ? a0 : 0.2f * a0;
      p0 += a0 * at[j];
    }
    p0 += __shfl_xor(p0, 1); p0 += __shfl_xor(p0, 2);
    float mn = fmaxf(m, p0);
    float sc = __expf(m - mn), ex = __expf(p0 - mn);
    den = den * sc + ex;
#pragma unroll
    for (int j = 0; j < 8; ++j) acc[j] = acc[j] * sc + ex * fl0[j];
    m = mn;
  }
  float inv = 1.f / den;
#pragma unroll
  for (int j = 0; j < 8; ++j) acc[j] = fmaxf(acc[j] * inv + bg[ch + j], 0.f);
  *(uint4*)&out[(size_t)node * 128 + ch] = pk8(acc);
}

// ---------------- pooled = column-sum(h7); out = pooled @ Wo + bo ----------------
// (diff-pool tail collapses: softmax over size-1 axis == 1; assignment rows sum to 1.)

__global__ __launch_bounds__(256) void pool_part_k(const ushort* __restrict__ h7,
                                                   float* __restrict__ part) {
  int bid = blockIdx.x;                 // NB*8 blocks
  int bgr = bid >> 3, seg = bid & 7;    // 128 rows/segment
  int t = threadIdx.x;
  int rg = t >> 5, cl = t & 31;
  const ushort* hb = h7 + (size_t)bgr * NN * 256;
  float a[8] = {};
  float f[8];
  for (int r = seg * 128 + rg; r < seg * 128 + 128; r += 8) {
    uint4 v = *(const uint4*)&hb[(size_t)r * 256 + cl * 8];
    up8(v, f);
#pragma unroll
    for (int j = 0; j < 8; ++j) a[j] += f[j];
  }
  __shared__ float red[8][256];
#pragma unroll
  for (int j = 0; j < 8; ++j) red[rg][cl * 8 + j] = a[j];
  __syncthreads();
  float s = 0.f;
#pragma unroll
  for (int g = 0; g < 8; ++g) s += red[g][t];
  part[(size_t)bid * 256 + t] = s;
}

__global__ __launch_bounds__(256) void pool_out_k(const float* __restrict__ part,
    const float* __restrict__ Wo, const float* __restrict__ bo, float* __restrict__ out) {
  int bgr = blockIdx.x, t = threadIdx.x;
  float s = 0.f;
#pragma unroll
  for (int g = 0; g < 8; ++g) s += part[(size_t)(bgr * 8 + g) * 256 + t];
  __shared__ float pv[256];
  pv[t] = s;
  __syncthreads();
  if (t < 8) {
    float o = bo[t];
    for (int c = 0; c < 256; ++c) o += pv[c] * Wo[c * 8 + t];
    out[bgr * 8 + t] = o;
  }
}

__global__ void zero_out_k(float* out, int n) {
  int g = blockIdx.x * 256 + threadIdx.x;
  if (g < n) out[g] = 0.f;
}

// ---------------- launch ----------------

extern "C" void kernel_launch(void* const* d_in, const int* in_sizes, int n_in,
                              void* d_out, int out_size, void* d_ws, size_t ws_size,
                              hipStream_t stream) {
  const float* x   = (const float*)d_in[0];
  const int*   ei  = (const int*)d_in[1];
  const float* ew  = (const float*)d_in[2];
  const float* W1  = (const float*)d_in[3];
  const float* b1  = (const float*)d_in[4];
  const float* W2  = (const float*)d_in[5];
  const float* b2  = (const float*)d_in[6];
  const float* W3  = (const float*)d_in[7];
  const float* b3  = (const float*)d_in[8];
  const float* W4  = (const float*)d_in[9];
  const float* b4  = (const float*)d_in[10];
  const float* Wl  = (const float*)d_in[11];
  const float* Wr  = (const float*)d_in[12];
  const float* att = (const float*)d_in[13];
  const float* bg  = (const float*)d_in[14];
  const float* Wg1 = (const float*)d_in[15];
  const float* Wm  = (const float*)d_in[16];
  const float* bm  = (const float*)d_in[17];
  const float* Wg2 = (const float*)d_in[18];
  const float* Wo  = (const float*)d_in[23];
  const float* bo  = (const float*)d_in[24];
  float* out = (float*)d_out;

  const int M = NB * NN;

  char* wp = (char*)d_ws;
  size_t used = 0;
  auto alloc = [&](size_t bytes) -> void* {
    void* p = (void*)wp;
    size_t a = (bytes + 255) & ~(size_t)255;
    wp += a; used += a;
    return p;
  };
  float* dinvw = (float*)alloc((size_t)NB * NN * 4);
  float* dinvu = (float*)alloc((size_t)NB * NN * 4);
  int*   rowptr= (int*)alloc((size_t)NB * (NN + 1) * 4);
  int*   psrc  = (int*)alloc((size_t)NB * NE * 4);
  float* pwn   = (float*)alloc((size_t)NB * NE * 4);
  float* pwu   = (float*)alloc((size_t)NB * NE * 4);
  float* part  = (float*)alloc((size_t)NB * 8 * 256 * 4);
  ushort* xbf  = (ushort*)alloc((size_t)M * 320 * 2);
  ushort* Wt1  = (ushort*)alloc((size_t)256 * 320 * 2);
  ushort* Wt2  = (ushort*)alloc((size_t)128 * 256 * 2);
  ushort* Wt3  = (ushort*)alloc((size_t)64 * 128 * 2);
  ushort* Wt4  = (ushort*)alloc((size_t)32 * 64 * 2);
  ushort* WtLR = (ushort*)alloc((size_t)256 * 32 * 2);
  ushort* Wtg1 = (ushort*)alloc((size_t)128 * 128 * 2);
  ushort* Wtm  = (ushort*)alloc((size_t)256 * 128 * 2);
  ushort* Wtg2 = (ushort*)alloc((size_t)256 * 256 * 2);
  ushort* B1 = (ushort*)alloc((size_t)M * 256 * 2);   // h1
  ushort* B2 = (ushort*)alloc((size_t)M * 256 * 2);
  ushort* B3 = (ushort*)alloc((size_t)M * 256 * 2);
  ushort* B4 = (ushort*)alloc((size_t)M * 256 * 2);   // xlr
  ushort* B2a = B2, *B2b = B2 + (size_t)M * 128;
  ushort* B3a = B3, *B3b = B3 + (size_t)M * 128;

  if (used > ws_size) {
    zero_out_k<<<(out_size + 255) / 256, 256, 0, stream>>>(out, out_size);
    return;
  }

  // ---- fused CSR build ----
  build_csr_k<<<NB, 1024, 0, stream>>>(ei, ew, dinvw, dinvu, rowptr, psrc, pwn, pwu);

  // ---- conversions ----
  xconv_k<<<M * 40 / 256, 256, 0, stream>>>(x, xbf);
  wconv_all_k<<<968, 256, 0, stream>>>(W1, W2, W3, W4, Wl, Wr, Wg1, Wm, Wg2,
                                       Wt1, Wt2, Wt3, Wt4, WtLR, Wtg1, Wtm, Wtg2);

  // ---- GCN stack ----
  mgemm_k<4,0><<<dim3(2, M / 128), 256, 0, stream>>>(xbf, Wt1, nullptr, B2, M, 320, 256);
  prop_k<256,0><<<M / 8, 256, 0, stream>>>(B2, B1, psrc, pwn, dinvw, rowptr, b1, nullptr);    // h1
  mgemm_k<4,0><<<dim3(1, M / 128), 256, 0, stream>>>(B1, Wt2, nullptr, B2a, M, 256, 128);
  prop_k<128,0><<<M / 16, 256, 0, stream>>>(B2a, B3a, psrc, pwn, dinvw, rowptr, b2, nullptr); // h2
  mgemm_k<2,0><<<dim3(1, M / 128), 256, 0, stream>>>(B3a, Wt3, nullptr, B2a, M, 128, 64);
  prop_k<64,0><<<M / 32, 256, 0, stream>>>(B2a, B3b, psrc, pwn, dinvw, rowptr, b3, nullptr);  // h3
  mgemm_k<1,0><<<dim3(1, M / 128), 256, 0, stream>>>(B3b, Wt4, nullptr, B2a, M, 64, 32);
  prop_k<32,0><<<M / 64, 256, 0, stream>>>(B2a, B2b, psrc, pwn, dinvw, rowptr, b4, nullptr);  // h4

  // ---- GATv2 (xl|xr one GEMM; fused flash-style attention) ----
  mgemm_k<4,0><<<dim3(2, M / 128), 256, 0, stream>>>(B2b, WtLR, nullptr, B4, M, 32, 256);     // xlr
  gat_fused_k<<<M / 16, 256, 0, stream>>>(B4, psrc, rowptr, att, bg, B2a);                    // hg

  // ---- GCN2Conv #1 (x0 = h2 = B3a) ----
  prop_k<128,1><<<M / 16, 256, 0, stream>>>(B2a, B2b, psrc, pwn, dinvw, rowptr, nullptr, B3a); // z1
  mgemm_k<4,2><<<dim3(1, M / 128), 256, 0, stream>>>(B2b, Wtg1, B2b, B2a, M, 128, 128);       // h5

  // ---- GCNConv mid (unweighted norm) ----
  mgemm_k<4,0><<<dim3(2, M / 128), 256, 0, stream>>>(B2a, Wtm, nullptr, B3, M, 128, 256);
  prop_k<256,0><<<M / 8, 256, 0, stream>>>(B3, B2, psrc, pwu, dinvu, rowptr, bm, nullptr);    // h6

  // ---- GCN2Conv #2 (x0 = h1 = B1) ----
  prop_k<256,1><<<M / 8, 256, 0, stream>>>(B2, B3, psrc, pwn, dinvw, rowptr, nullptr, B1);    // z2
  mgemm_k<4,2><<<dim3(2, M / 128), 256, 0, stream>>>(B3, Wtg2, B3, B2, M, 256, 256);          // h7

  // ---- collapsed diff-pool + output projection ----
  pool_part_k<<<NB * 8, 256, 0, stream>>>(B2, part);
  pool_out_k<<<NB, 256, 0, stream>>>(part, Wo, bo, out);
}

// Round 7
// 491.977 us; speedup vs baseline: 6.8812x; 1.0869x over previous
//
#include <hip/hip_runtime.h>
#include <cstdint>
#include <cstddef>

constexpr int NB = 64;     // graphs
constexpr int NN = 1024;   // nodes/graph
constexpr int NE = 16384;  // edges/graph
constexpr int NCH = 8;     // CSR-build chunks per graph
constexpr int CHE = NE / NCH;
constexpr float C_BETA = 0.04879016417f;   // log(0.1/2 + 1)

typedef __attribute__((ext_vector_type(8))) short s8v;   // 8 bf16 (4 VGPRs)
typedef __attribute__((ext_vector_type(4))) float f4v;

__device__ inline float bf2f(ushort u){ union{uint u;float f;} v; v.u=((uint)u)<<16; return v.f; }
__device__ inline ushort f2bf(float f){ union{float f;uint u;} v; v.f=f; uint r=v.u+0x7fffu+((v.u>>16)&1u); return (ushort)(r>>16); }
__device__ inline void up8(uint4 x, float* o){
  o[0]=bf2f((ushort)x.x); o[1]=bf2f((ushort)(x.x>>16));
  o[2]=bf2f((ushort)x.y); o[3]=bf2f((ushort)(x.y>>16));
  o[4]=bf2f((ushort)x.z); o[5]=bf2f((ushort)(x.z>>16));
  o[6]=bf2f((ushort)x.w); o[7]=bf2f((ushort)(x.w>>16));
}
__device__ inline uint pk2(float a, float b){ return (uint)f2bf(a) | ((uint)f2bf(b)<<16); }
__device__ inline uint4 pk8(const float* f){
  uint4 v; v.x=pk2(f[0],f[1]); v.y=pk2(f[2],f[3]); v.z=pk2(f[4],f[5]); v.w=pk2(f[6],f[7]); return v;
}
// XCD-bijective swizzle: graph g -> XCD g/(NB/8); requires grid = NB*bpg
__device__ inline int swz8(int bid, int bpg){
  int xcd = bid & 7, j = bid >> 3;
  return (xcd * (NB/8) + j / bpg) * bpg + (j % bpg);
}

// ---------------- CSR build: 2-pass counting sort, full-GPU width ----------------
// Pass A: per-chunk private LDS histograms (count + weighted degree).

__global__ __launch_bounds__(256) void hist_k(const int* __restrict__ ei,
    const float* __restrict__ ew, int* __restrict__ phist, float* __restrict__ pdegw) {
  int blk = blockIdx.x;               // NB*NCH
  int b = blk >> 3, ch = blk & 7;
  __shared__ int hc[NN];
  __shared__ float hw[NN];
  int t = threadIdx.x;
  for (int i = t; i < NN; i += 256) { hc[i] = 0; hw[i] = 0.f; }
  __syncthreads();
  const int* dstb = ei + (size_t)b * 2 * NE + NE + ch * CHE;
  const float* ewb = ew + (size_t)b * NE + ch * CHE;
  for (int e = t; e < CHE; e += 256) {
    int d = dstb[e];
    atomicAdd(&hc[d], 1);
    atomicAdd(&hw[d], ewb[e]);
  }
  __syncthreads();
  size_t o = ((size_t)b * NCH + ch) * NN;
  for (int i = t; i < NN; i += 256) {
    phist[o + i] = hc[i];
    pdegw[o + i] = hw[i];
  }
}

// Pass B: per-graph reduce partials -> dinv, rowptr scan, and in-place
// conversion of phist into absolute per-chunk scatter bases.

__global__ __launch_bounds__(1024) void scan2_k(int* __restrict__ phist,
    const float* __restrict__ pdegw, float* __restrict__ dinvw,
    float* __restrict__ dinvu, int* __restrict__ rowptr) {
  int b = blockIdx.x, t = threadIdx.x;
  size_t base = (size_t)b * NCH * NN;
  int h[NCH];
  int cnt = 0; float dw = 1.0f;   // self-loop weight 1
#pragma unroll
  for (int c = 0; c < NCH; ++c) {
    h[c] = phist[base + c * NN + t];
    cnt += h[c];
    dw += pdegw[base + c * NN + t];
  }
  dinvw[b * NN + t] = rsqrtf(dw);
  dinvu[b * NN + t] = rsqrtf(1.0f + (float)cnt);
  __shared__ int ss[NN];
  ss[t] = cnt;
  __syncthreads();
  for (int off = 1; off < NN; off <<= 1) {
    int xv = (t >= off) ? ss[t - off] : 0;
    __syncthreads();
    ss[t] += xv;
    __syncthreads();
  }
  rowptr[b * (NN + 1) + t + 1] = ss[t];
  if (t == 0) rowptr[b * (NN + 1)] = 0;
  int excl = ss[t] - cnt;
#pragma unroll
  for (int c = 0; c < NCH; ++c) {   // absolute base of chunk c's slice of node t
    phist[base + c * NN + t] = excl;
    excl += h[c];
  }
}

// Pass C: per-chunk scatter with block-private LDS fill counters; packed 16B edges.

__global__ __launch_bounds__(256) void scatter2_k(const int* __restrict__ ei,
    const float* __restrict__ ew, const int* __restrict__ coff,
    const float* __restrict__ dinvw, const float* __restrict__ dinvu,
    int4* __restrict__ pedge) {
  int blk = blockIdx.x;
  int b = blk >> 3, ch = blk & 7;
  __shared__ int sbase[NN];
  __shared__ int sfill[NN];
  __shared__ float sdw[NN];
  __shared__ float sdu[NN];
  int t = threadIdx.x;
  for (int i = t; i < NN; i += 256) {
    sbase[i] = coff[((size_t)b * NCH + ch) * NN + i];
    sfill[i] = 0;
    sdw[i] = dinvw[b * NN + i];
    sdu[i] = dinvu[b * NN + i];
  }
  __syncthreads();
  const int* srcb = ei + (size_t)b * 2 * NE + ch * CHE;
  const int* dstb = ei + (size_t)b * 2 * NE + NE + ch * CHE;
  const float* ewb = ew + (size_t)b * NE + ch * CHE;
  int4* peb = pedge + (size_t)b * NE;
  for (int e = t; e < CHE; e += 256) {
    int s = srcb[e], d = dstb[e];
    int pos = sbase[d] + atomicAdd(&sfill[d], 1);
    int4 pk;
    pk.x = s;
    pk.y = __float_as_int(sdw[s] * ewb[e] * sdw[d]);
    pk.z = __float_as_int(sdu[s] * sdu[d]);
    pk.w = 0;
    peb[pos] = pk;
  }
}

// ---------------- conversions ----------------

__global__ void xconv_k(const float* __restrict__ x, ushort* __restrict__ xbf) {
  int g = blockIdx.x * 256 + threadIdx.x;   // M*40 threads, 8 cols each
  int row = g / 40, c = (g % 40) * 8;
  float f[8];
  const float* xr = x + (size_t)row * 300;
  if (c + 8 <= 300) {
    float4 a = *(const float4*)&xr[c];
    float4 bq = *(const float4*)&xr[c + 4];
    f[0]=a.x; f[1]=a.y; f[2]=a.z; f[3]=a.w;
    f[4]=bq.x; f[5]=bq.y; f[6]=bq.z; f[7]=bq.w;
  } else {
#pragma unroll
    for (int j = 0; j < 8; ++j) f[j] = (c + j < 300) ? xr[c + j] : 0.f;
  }
  *(uint4*)&xbf[(size_t)row * 320 + c] = pk8(f);
}

__device__ inline void wcv(const float* __restrict__ W, ushort* __restrict__ Wt,
                           int idx, int K, int N, int Kp) {
  int n = idx / Kp, k = idx % Kp;
  Wt[idx] = (k < K) ? f2bf(W[(size_t)k * N + n]) : (ushort)0;
}

// all weight transposes in one launch (grid = 968 blocks x 256)
__global__ void wconv_all_k(const float* W1, const float* W2, const float* W3,
                            const float* W4, const float* Wl, const float* Wr,
                            const float* Wg1, const float* Wm, const float* Wg2,
                            ushort* Wt1, ushort* Wt2, ushort* Wt3, ushort* Wt4,
                            ushort* WtLR, ushort* Wtg1, ushort* Wtm, ushort* Wtg2) {
  int bb = blockIdx.x, t = threadIdx.x;
  if      (bb < 320) wcv(W1, Wt1, bb * 256 + t, 300, 256, 320);
  else if (bb < 448) wcv(W2, Wt2, (bb - 320) * 256 + t, 256, 128, 256);
  else if (bb < 480) wcv(W3, Wt3, (bb - 448) * 256 + t, 128, 64, 128);
  else if (bb < 488) wcv(W4, Wt4, (bb - 480) * 256 + t, 64, 32, 64);
  else if (bb < 504) wcv(Wl, WtLR, (bb - 488) * 256 + t, 32, 128, 32);
  else if (bb < 520) wcv(Wr, WtLR + 128 * 32, (bb - 504) * 256 + t, 32, 128, 32);
  else if (bb < 584) wcv(Wg1, Wtg1, (bb - 520) * 256 + t, 128, 128, 128);
  else if (bb < 712) wcv(Wm, Wtm, (bb - 584) * 256 + t, 128, 256, 128);
  else               wcv(Wg2, Wtg2, (bb - 712) * 256 + t, 256, 256, 256);
}

// ---------------- MFMA bf16 GEMM: C[M,N] = A[M,K] @ W[K,N]  (Wt = W^T bf16) ----------------
// MODE 0: C = acc (bf16).  MODE 2: C = relu((1-beta)*Z + beta*acc) (GCN2 epilogue).

template<int NI, int MODE>
__global__ __launch_bounds__(256) void mgemm_k(const ushort* __restrict__ A,
    const ushort* __restrict__ Bt, const ushort* __restrict__ Z,
    ushort* __restrict__ C, int M, int K, int N) {
  constexpr int BN = NI * 32;
  __shared__ ushort As[128][40];   // pad to 80B rows: 2-way-free bank pattern
  __shared__ ushort Bs[BN][40];
  int tid = threadIdx.x;
  int wave = tid >> 6, lane = tid & 63;
  int bm = blockIdx.y * 128, bn = blockIdx.x * BN;
  int wm = (wave >> 1) * 64, wn = (wave & 1) * (NI * 16);
  f4v acc[4][NI];
#pragma unroll
  for (int a = 0; a < 4; ++a)
#pragma unroll
    for (int b = 0; b < NI; ++b)
#pragma unroll
      for (int q = 0; q < 4; ++q) acc[a][b][q] = 0.f;
  int r = lane & 15, kg = (lane >> 4) * 8;
  for (int k0 = 0; k0 < K; k0 += 32) {
#pragma unroll
    for (int c = tid; c < 512; c += 256) {
      int row = c >> 2, kc = (c & 3) * 8;
      *(uint4*)&As[row][kc] = *(const uint4*)&A[(size_t)(bm + row) * K + k0 + kc];
    }
#pragma unroll
    for (int c = tid; c < BN * 4; c += 256) {
      int col = c >> 2, kc = (c & 3) * 8;
      *(uint4*)&Bs[col][kc] = *(const uint4*)&Bt[(size_t)(bn + col) * K + k0 + kc];
    }
    __syncthreads();
    s8v af[4], bf[NI];
#pragma unroll
    for (int mi = 0; mi < 4; ++mi) af[mi] = *(const s8v*)&As[wm + mi * 16 + r][kg];
#pragma unroll
    for (int ni = 0; ni < NI; ++ni) bf[ni] = *(const s8v*)&Bs[wn + ni * 16 + r][kg];
#pragma unroll
    for (int mi = 0; mi < 4; ++mi)
#pragma unroll
      for (int ni = 0; ni < NI; ++ni)
        acc[mi][ni] = __builtin_amdgcn_mfma_f32_16x16x32_bf16(af[mi], bf[ni], acc[mi][ni], 0, 0, 0);
    __syncthreads();
  }
  int col = lane & 15, rowg = (lane >> 4) * 4;
#pragma unroll
  for (int mi = 0; mi < 4; ++mi)
#pragma unroll
    for (int ni = 0; ni < NI; ++ni)
#pragma unroll
      for (int q = 0; q < 4; ++q) {
        int row = bm + wm + mi * 16 + rowg + q;
        int cc = bn + wn + ni * 16 + col;
        size_t idx = (size_t)row * N + cc;
        float v = acc[mi][ni][q];
        if (MODE == 2) v = fmaxf((1.f - C_BETA) * bf2f(Z[idx]) + C_BETA * v, 0.f);
        C[idx] = f2bf(v);
      }
}

// ---------------- graph propagation (packed dst-CSR gather, bf16 I/O) ----------------
// acc = dinv[i]^2*in[i,:] + sum_p w[p]*in[src[p],:]   (w from packed edge: .y=wn, .z=wu)
// MODE 0: out = relu(acc + bias).  MODE 1: out = 0.5*acc + 0.5*x0.

template<int D, int MODE, int WSEL>
__global__ __launch_bounds__(256) void prop_k(const ushort* __restrict__ in,
    ushort* __restrict__ out, const int4* __restrict__ pedge,
    const float* __restrict__ dinv, const int* __restrict__ rowptr,
    const float* __restrict__ bias, const ushort* __restrict__ x0) {
  constexpr int TPN = D / 8, NPB = 256 / TPN, BPG = NN / NPB;
  int t = threadIdx.x;
  int bid = swz8(blockIdx.x, BPG);
  int tn = t / TPN, cl = t % TPN;
  int node = bid * NPB + tn;
  int b = node >> 10, i = node & 1023;
  float di = dinv[node];
  float f[8], acc[8];
  uint4 ov = *(const uint4*)&in[(size_t)node * D + cl * 8];
  up8(ov, f);
  float w0 = di * di;
#pragma unroll
  for (int j = 0; j < 8; ++j) acc[j] = w0 * f[j];
  int r0 = rowptr[b * (NN + 1) + i], r1 = rowptr[b * (NN + 1) + i + 1];
  const int4* pe = pedge + (size_t)b * NE;
  const ushort* inb = in + (size_t)b * NN * D;
  int p = r0;
  for (; p + 4 <= r1; p += 4) {      // 4-way unroll: independent loads
    int4 e0 = pe[p], e1 = pe[p + 1], e2 = pe[p + 2], e3 = pe[p + 3];
    float wa = __int_as_float(WSEL ? e0.z : e0.y);
    float wb2 = __int_as_float(WSEL ? e1.z : e1.y);
    float wc = __int_as_float(WSEL ? e2.z : e2.y);
    float wd = __int_as_float(WSEL ? e3.z : e3.y);
    uint4 rv0 = *(const uint4*)&inb[(size_t)e0.x * D + cl * 8];
    uint4 rv1 = *(const uint4*)&inb[(size_t)e1.x * D + cl * 8];
    uint4 rv2 = *(const uint4*)&inb[(size_t)e2.x * D + cl * 8];
    uint4 rv3 = *(const uint4*)&inb[(size_t)e3.x * D + cl * 8];
    up8(rv0, f);
#pragma unroll
    for (int j = 0; j < 8; ++j) acc[j] += wa * f[j];
    up8(rv1, f);
#pragma unroll
    for (int j = 0; j < 8; ++j) acc[j] += wb2 * f[j];
    up8(rv2, f);
#pragma unroll
    for (int j = 0; j < 8; ++j) acc[j] += wc * f[j];
    up8(rv3, f);
#pragma unroll
    for (int j = 0; j < 8; ++j) acc[j] += wd * f[j];
  }
  for (; p < r1; ++p) {
    int4 e = pe[p];
    float w = __int_as_float(WSEL ? e.z : e.y);
    uint4 rv = *(const uint4*)&inb[(size_t)e.x * D + cl * 8];
    up8(rv, f);
#pragma unroll
    for (int j = 0; j < 8; ++j) acc[j] += w * f[j];
  }
  size_t ob = (size_t)node * D + cl * 8;
  if (MODE == 0) {
#pragma unroll
    for (int j = 0; j < 8; ++j) acc[j] = fmaxf(acc[j] + bias[cl * 8 + j], 0.f);
  } else {
    uint4 xv = *(const uint4*)&x0[ob];
    up8(xv, f);
#pragma unroll
    for (int j = 0; j < 8; ++j) acc[j] = 0.5f * acc[j] + 0.5f * f[j];
  }
  *(uint4*)&out[ob] = pk8(acc);
}

// ---------------- GATv2: fused flash-style (logit + online softmax + gather) ----------------
// xlr layout: [node][256]: ch 0-127 = xl, 128-255 = xr.

__global__ __launch_bounds__(256) void gat_fused_k(const ushort* __restrict__ xlr,
    const int4* __restrict__ pedge, const int* __restrict__ rowptr,
    const float* __restrict__ att, const float* __restrict__ bg,
    ushort* __restrict__ out) {
  int bid = swz8(blockIdx.x, NN / 16);   // 16 nodes/block
  int t = threadIdx.x;
  int tn = t >> 4, cl = t & 15;
  int node = bid * 16 + tn;
  int b = node >> 10, i = node & 1023;
  int ch = cl * 8;
  int r0 = rowptr[b * (NN + 1) + i], r1 = rowptr[b * (NN + 1) + i + 1];
  const ushort* xb = xlr + (size_t)b * NN * 256;
  const int4* pe = pedge + (size_t)b * NE;
  float fr[8], at[8];
  {
    uint4 rv = *(const uint4*)&xb[(size_t)i * 256 + 128 + ch];  // xr[i] chunk
    up8(rv, fr);
#pragma unroll
    for (int j = 0; j < 8; ++j) at[j] = att[ch + j];   // flat att == ch+j
  }
  float m, den, acc[8];
  {
    float fs[8];
    uint4 sv = *(const uint4*)&xb[(size_t)i * 256 + ch];        // xl[i] (self)
    up8(sv, fs);
    float part = 0.f;
#pragma unroll
    for (int j = 0; j < 8; ++j) {
      float v = fs[j] + fr[j];
      v = v > 0.f ? v : 0.2f * v;
      part += v * at[j];
    }
    part += __shfl_xor(part, 1);
    part += __shfl_xor(part, 2);
    m = part; den = 1.f;
#pragma unroll
    for (int j = 0; j < 8; ++j) acc[j] = fs[j];
  }
  float fl0[8], fl1[8];
  int p = r0;
  for (; p + 2 <= r1; p += 2) {
    int s0 = pe[p].x, s1 = pe[p + 1].x;
    uint4 v0 = *(const uint4*)&xb[(size_t)s0 * 256 + ch];
    uint4 v1 = *(const uint4*)&xb[(size_t)s1 * 256 + ch];
    up8(v0, fl0); up8(v1, fl1);
    float p0 = 0.f, p1 = 0.f;
#pragma unroll
    for (int j = 0; j < 8; ++j) {
      float a0 = fl0[j] + fr[j]; a0 = a0 > 0.f ? a0 : 0.2f * a0;
      float a1 = fl1[j] + fr[j]; a1 = a1 > 0.f ? a1 : 0.2f * a1;
      p0 += a0 * at[j]; p1 += a1 * at[j];
    }
    p0 += __shfl_xor(p0, 1); p0 += __shfl_xor(p0, 2);
    p1 += __shfl_xor(p1, 1); p1 += __shfl_xor(p1, 2);
    {
      float mn = fmaxf(m, p0);
      float sc = __expf(m - mn), ex = __expf(p0 - mn);
      den = den * sc + ex;
#pragma unroll
      for (int j = 0; j < 8; ++j) acc[j] = acc[j] * sc + ex * fl0[j];
      m = mn;
    }
    {
      float mn = fmaxf(m, p1);
      float sc = __expf(m - mn), ex = __expf(p1 - mn);
      den = den * sc + ex;
#pragma unroll
      for (int j = 0; j < 8; ++j) acc[j] = acc[j] * sc + ex * fl1[j];
      m = mn;
    }
  }
  if (p < r1) {
    int s = pe[p].x;
    uint4 v0 = *(const uint4*)&xb[(size_t)s * 256 + ch];
    up8(v0, fl0);
    float p0 = 0.f;
#pragma unroll
    for (int j = 0; j < 8; ++j) {
      float a0 = fl0[j] + fr[j]; a0 = a0 > 0.f ? a0 : 0.2f * a0;
      p0 += a0 * at[j];
    }
    p0 += __shfl_xor(p0, 1); p0 += __shfl_xor(p0, 2);
    float mn = fmaxf(m, p0);
    float sc = __expf(m - mn), ex = __expf(p0 - mn);
    den = den * sc + ex;
#pragma unroll
    for (int j = 0; j < 8; ++j) acc[j] = acc[j] * sc + ex * fl0[j];
    m = mn;
  }
  float inv = 1.f / den;
#pragma unroll
  for (int j = 0; j < 8; ++j) acc[j] = fmaxf(acc[j] * inv + bg[ch + j], 0.f);
  *(uint4*)&out[(size_t)node * 128 + ch] = pk8(acc);
}

// ---------------- pooled = column-sum(h7); out = pooled @ Wo + bo ----------------
// (diff-pool tail collapses: softmax over size-1 axis == 1; assignment rows sum to 1.)

__global__ __launch_bounds__(256) void pool_part_k(const ushort* __restrict__ h7,
                                                   float* __restrict__ part) {
  int bid = blockIdx.x;                 // NB*8 blocks
  int bgr = bid >> 3, seg = bid & 7;    // 128 rows/segment
  int t = threadIdx.x;
  int rg = t >> 5, cl = t & 31;
  const ushort* hb = h7 + (size_t)bgr * NN * 256;
  float a[8] = {};
  float f[8];
  for (int r = seg * 128 + rg; r < seg * 128 + 128; r += 8) {
    uint4 v = *(const uint4*)&hb[(size_t)r * 256 + cl * 8];
    up8(v, f);
#pragma unroll
    for (int j = 0; j < 8; ++j) a[j] += f[j];
  }
  __shared__ float red[8][256];
#pragma unroll
  for (int j = 0; j < 8; ++j) red[rg][cl * 8 + j] = a[j];
  __syncthreads();
  float s = 0.f;
#pragma unroll
  for (int g = 0; g < 8; ++g) s += red[g][t];
  part[(size_t)bid * 256 + t] = s;
}

__global__ __launch_bounds__(256) void pool_out_k(const float* __restrict__ part,
    const float* __restrict__ Wo, const float* __restrict__ bo, float* __restrict__ out) {
  int bgr = blockIdx.x, t = threadIdx.x;
  float s = 0.f;
#pragma unroll
  for (int g = 0; g < 8; ++g) s += part[(size_t)(bgr * 8 + g) * 256 + t];
  __shared__ float pv[256];
  pv[t] = s;
  __syncthreads();
  if (t < 8) {
    float o = bo[t];
    for (int c = 0; c < 256; ++c) o += pv[c] * Wo[c * 8 + t];
    out[bgr * 8 + t] = o;
  }
}

__global__ void zero_out_k(float* out, int n) {
  int g = blockIdx.x * 256 + threadIdx.x;
  if (g < n) out[g] = 0.f;
}

// ---------------- launch ----------------

extern "C" void kernel_launch(void* const* d_in, const int* in_sizes, int n_in,
                              void* d_out, int out_size, void* d_ws, size_t ws_size,
                              hipStream_t stream) {
  const float* x   = (const float*)d_in[0];
  const int*   ei  = (const int*)d_in[1];
  const float* ew  = (const float*)d_in[2];
  const float* W1  = (const float*)d_in[3];
  const float* b1  = (const float*)d_in[4];
  const float* W2  = (const float*)d_in[5];
  const float* b2  = (const float*)d_in[6];
  const float* W3  = (const float*)d_in[7];
  const float* b3  = (const float*)d_in[8];
  const float* W4  = (const float*)d_in[9];
  const float* b4  = (const float*)d_in[10];
  const float* Wl  = (const float*)d_in[11];
  const float* Wr  = (const float*)d_in[12];
  const float* att = (const float*)d_in[13];
  const float* bg  = (const float*)d_in[14];
  const float* Wg1 = (const float*)d_in[15];
  const float* Wm  = (const float*)d_in[16];
  const float* bm  = (const float*)d_in[17];
  const float* Wg2 = (const float*)d_in[18];
  const float* Wo  = (const float*)d_in[23];
  const float* bo  = (const float*)d_in[24];
  float* out = (float*)d_out;

  const int M = NB * NN;

  char* wp = (char*)d_ws;
  size_t used = 0;
  auto alloc = [&](size_t bytes) -> void* {
    void* p = (void*)wp;
    size_t a = (bytes + 255) & ~(size_t)255;
    wp += a; used += a;
    return p;
  };
  float* dinvw = (float*)alloc((size_t)NB * NN * 4);
  float* dinvu = (float*)alloc((size_t)NB * NN * 4);
  int*   rowptr= (int*)alloc((size_t)NB * (NN + 1) * 4);
  int*   phist = (int*)alloc((size_t)NB * NCH * NN * 4);
  float* pdegw = (float*)alloc((size_t)NB * NCH * NN * 4);
  int4*  pedge = (int4*)alloc((size_t)NB * NE * 16);
  float* part  = (float*)alloc((size_t)NB * 8 * 256 * 4);
  ushort* xbf  = (ushort*)alloc((size_t)M * 320 * 2);
  ushort* Wt1  = (ushort*)alloc((size_t)256 * 320 * 2);
  ushort* Wt2  = (ushort*)alloc((size_t)128 * 256 * 2);
  ushort* Wt3  = (ushort*)alloc((size_t)64 * 128 * 2);
  ushort* Wt4  = (ushort*)alloc((size_t)32 * 64 * 2);
  ushort* WtLR = (ushort*)alloc((size_t)256 * 32 * 2);
  ushort* Wtg1 = (ushort*)alloc((size_t)128 * 128 * 2);
  ushort* Wtm  = (ushort*)alloc((size_t)256 * 128 * 2);
  ushort* Wtg2 = (ushort*)alloc((size_t)256 * 256 * 2);
  ushort* B1 = (ushort*)alloc((size_t)M * 256 * 2);   // h1
  ushort* B2 = (ushort*)alloc((size_t)M * 256 * 2);
  ushort* B3 = (ushort*)alloc((size_t)M * 256 * 2);
  ushort* B4 = (ushort*)alloc((size_t)M * 256 * 2);   // xlr
  ushort* B2a = B2, *B2b = B2 + (size_t)M * 128;
  ushort* B3a = B3, *B3b = B3 + (size_t)M * 128;

  if (used > ws_size) {
    zero_out_k<<<(out_size + 255) / 256, 256, 0, stream>>>(out, out_size);
    return;
  }

  // ---- CSR build (2-pass counting sort) ----
  hist_k<<<NB * NCH, 256, 0, stream>>>(ei, ew, phist, pdegw);
  scan2_k<<<NB, 1024, 0, stream>>>(phist, pdegw, dinvw, dinvu, rowptr);
  scatter2_k<<<NB * NCH, 256, 0, stream>>>(ei, ew, phist, dinvw, dinvu, pedge);

  // ---- conversions ----
  xconv_k<<<M * 40 / 256, 256, 0, stream>>>(x, xbf);
  wconv_all_k<<<968, 256, 0, stream>>>(W1, W2, W3, W4, Wl, Wr, Wg1, Wm, Wg2,
                                       Wt1, Wt2, Wt3, Wt4, WtLR, Wtg1, Wtm, Wtg2);

  // ---- GCN stack ----
  mgemm_k<4,0><<<dim3(2, M / 128), 256, 0, stream>>>(xbf, Wt1, nullptr, B2, M, 320, 256);
  prop_k<256,0,0><<<M / 8, 256, 0, stream>>>(B2, B1, pedge, dinvw, rowptr, b1, nullptr);    // h1
  mgemm_k<4,0><<<dim3(1, M / 128), 256, 0, stream>>>(B1, Wt2, nullptr, B2a, M, 256, 128);
  prop_k<128,0,0><<<M / 16, 256, 0, stream>>>(B2a, B3a, pedge, dinvw, rowptr, b2, nullptr); // h2
  mgemm_k<2,0><<<dim3(1, M / 128), 256, 0, stream>>>(B3a, Wt3, nullptr, B2a, M, 128, 64);
  prop_k<64,0,0><<<M / 32, 256, 0, stream>>>(B2a, B3b, pedge, dinvw, rowptr, b3, nullptr);  // h3
  mgemm_k<1,0><<<dim3(1, M / 128), 256, 0, stream>>>(B3b, Wt4, nullptr, B2a, M, 64, 32);
  prop_k<32,0,0><<<M / 64, 256, 0, stream>>>(B2a, B2b, pedge, dinvw, rowptr, b4, nullptr);  // h4

  // ---- GATv2 (xl|xr one GEMM; fused flash-style attention) ----
  mgemm_k<4,0><<<dim3(2, M / 128), 256, 0, stream>>>(B2b, WtLR, nullptr, B4, M, 32, 256);   // xlr
  gat_fused_k<<<M / 16, 256, 0, stream>>>(B4, pedge, rowptr, att, bg, B2a);                 // hg

  // ---- GCN2Conv #1 (x0 = h2 = B3a) ----
  prop_k<128,1,0><<<M / 16, 256, 0, stream>>>(B2a, B2b, pedge, dinvw, rowptr, nullptr, B3a); // z1
  mgemm_k<4,2><<<dim3(1, M / 128), 256, 0, stream>>>(B2b, Wtg1, B2b, B2a, M, 128, 128);     // h5

  // ---- GCNConv mid (unweighted norm) ----
  mgemm_k<4,0><<<dim3(2, M / 128), 256, 0, stream>>>(B2a, Wtm, nullptr, B3, M, 128, 256);
  prop_k<256,0,1><<<M / 8, 256, 0, stream>>>(B3, B2, pedge, dinvu, rowptr, bm, nullptr);    // h6

  // ---- GCN2Conv #2 (x0 = h1 = B1) ----
  prop_k<256,1,0><<<M / 8, 256, 0, stream>>>(B2, B3, pedge, dinvw, rowptr, nullptr, B1);    // z2
  mgemm_k<4,2><<<dim3(2, M / 128), 256, 0, stream>>>(B3, Wtg2, B3, B2, M, 256, 256);        // h7

  // ---- collapsed diff-pool + output projection ----
  pool_part_k<<<NB * 8, 256, 0, stream>>>(B2, part);
  pool_out_k<<<NB, 256, 0, stream>>>(part, Wo, bo, out);
}